// Round 4
// baseline (835.540 us; speedup 1.0000x reference)
//
#include <hip/hip_runtime.h>

#define NN 200000
#define NEGV -1000000000.0f

typedef __attribute__((ext_vector_type(8))) short bf16x8;
typedef __attribute__((ext_vector_type(4))) float f32x4;

__device__ __forceinline__ float bf2f(unsigned short u){
  unsigned int x = ((unsigned int)u) << 16;
  return __builtin_bit_cast(float, x);
}
__device__ __forceinline__ unsigned short f2bf(float f){
  unsigned int x = __builtin_bit_cast(unsigned int, f);
  x += 0x7fffu + ((x >> 16) & 1u);
  return (unsigned short)(x >> 16);
}
__device__ __forceinline__ void gload16(const void* g, void* l){
  __builtin_amdgcn_global_load_lds((const __attribute__((address_space(1))) unsigned int*)g,
                                   (__attribute__((address_space(3))) unsigned int*)l, 16, 0, 0);
}

// ---------------- workspace layout (bytes) ----------------
static constexpr size_t OFF_RK     = 0;
static constexpr size_t OFF_RV     = 800256;
static constexpr size_t OFF_LOGITS = 1600512;   // [n][8] f32
static constexpr size_t OFF_SCORES = 8000512;
static constexpr size_t OFF_A2     = 8802816;
static constexpr size_t OFF_CONSTS = 8811008;
static constexpr size_t OFF_BIMG   = 8811264;   // 8*528*64
static constexpr size_t OFF_LSTAT  = 9081600;   // 128*8*2 f32
static constexpr size_t OFF_MZ     = 9089792;
static constexpr size_t OFF_KATTN  = 9089856;
static constexpr size_t OFF_KB     = 9090880;
static constexpr size_t OFF_UPART  = 9090944;   // 512*2048 f32
static constexpr size_t OFF_TPART  = 13285248;  // 512*8 f32
static constexpr size_t OFF_U      = 13301632;
static constexpr size_t OFF_T      = 13309824;
static constexpr size_t OFF_P3STAT = 13309888;  // 512*2
static constexpr size_t OFF_MZ3    = 13313984;
static constexpr size_t OFF_EMBBF  = 13314048;  // N*256 bf16 = 102.4MB
static constexpr size_t WS_NEED_BF = OFF_EMBBF + (size_t)NN*512;

// ---------------- fused prep: query -> q2 -> A -> A2/consts (1 block) ----------------
__global__ void k_prep(const float* __restrict__ ctx, const float* __restrict__ Wc,
                       const float* __restrict__ bc, const float* __restrict__ ipw,
                       const float* __restrict__ ipb, const float* __restrict__ Wk,
                       const float* __restrict__ bk, float* __restrict__ A2,
                       float* __restrict__ consts){
  int t = threadIdx.x, lane = t & 63, wave = t >> 6;
  __shared__ float ctxs[768], querys[256], q2s[256], AHs[256];
  __shared__ float red2[4], red3[4];
  #pragma unroll
  for (int r = 0; r < 3; r++) ctxs[r*256 + t] = ctx[r*256 + t];
  __syncthreads();
  for (int rr = 0; rr < 64; rr++){
    int r = wave*64 + rr;
    float d = 0.f;
    #pragma unroll
    for (int it = 0; it < 12; it++) d += ctxs[it*64 + lane] * Wc[r*768 + it*64 + lane];
    #pragma unroll
    for (int m = 1; m < 64; m <<= 1) d += __shfl_xor(d, m);
    if (lane == 0) querys[r] = d + bc[r];
  }
  __syncthreads();
  for (int rr = 0; rr < 64; rr++){
    int r = wave*64 + rr;
    float d = 0.f;
    #pragma unroll
    for (int it = 0; it < 4; it++) d += querys[it*64 + lane] * ipw[r*256 + it*64 + lane];
    #pragma unroll
    for (int m = 1; m < 64; m <<= 1) d += __shfl_xor(d, m);
    if (lane == 0) q2s[r] = d + ipb[r];
  }
  __syncthreads();
  for (int h = 0; h < 8; h++){
    float a = 0.f;
    #pragma unroll
    for (int d = 0; d < 32; d++) a += q2s[h*32 + d] * ipw[(256 + h*32 + d)*256 + t];
    __syncthreads();              // prior AHs readers done
    AHs[t] = a;
    float v = (t < 32) ? q2s[h*32 + t] * ipb[256 + h*32 + t] : 0.f;
    #pragma unroll
    for (int m = 1; m < 64; m <<= 1) v += __shfl_xor(v, m);
    if (lane == 0) red2[wave] = v;
    __syncthreads();              // AHs + red2 visible
    if (t == 0) consts[8 + h] = red2[0] + red2[1] + red2[2] + red2[3];
    float a2 = 0.f;
    for (int e = 0; e < 256; e++) a2 += AHs[e] * Wk[e*256 + t];
    A2[h*256 + t] = a2;
    float cc = AHs[t] * bk[t];
    #pragma unroll
    for (int m = 1; m < 64; m <<= 1) cc += __shfl_xor(cc, m);
    if (lane == 0) red3[wave] = cc;
    __syncthreads();
    if (t == 0) consts[h] = red3[0] + red3[1] + red3[2] + red3[3];
  }
}

// Pre-swizzled bf16 B image: per k-step s (8), col (528: Wk|Wv|A2+pad), kg (4):
// 16B granule at s*33792 + ((col*64 + kg*16) ^ ((col&7)<<4))
__global__ void k_bimg(const float* __restrict__ Wk, const float* __restrict__ Wv,
                       const float* __restrict__ A2, unsigned char* __restrict__ bimg){
  int g = blockIdx.x*256 + threadIdx.x;
  if (g >= 8*528*4) return;
  int s = g / (528*4);
  int rem = g % (528*4);
  int col = rem >> 2, kg = rem & 3;
  int j0 = s*32 + kg*8;
  const float* src = nullptr;
  if (col < 256) src = Wk + col*256 + j0;
  else if (col < 512) src = Wv + (col-256)*256 + j0;
  else if (col < 520) src = A2 + (col-512)*256 + j0;
  unsigned short u[8];
  #pragma unroll
  for (int i = 0; i < 8; i++) u[i] = src ? f2bf(src[i]) : (unsigned short)0;
  uint4 o;
  o.x = (unsigned int)u[0] | ((unsigned int)u[1] << 16);
  o.y = (unsigned int)u[2] | ((unsigned int)u[3] << 16);
  o.z = (unsigned int)u[4] | ((unsigned int)u[5] << 16);
  o.w = (unsigned int)u[6] | ((unsigned int)u[7] << 16);
  unsigned int addr = (unsigned int)((col*64 + kg*16) ^ ((col & 7) << 4));
  *(uint4*)(bimg + (size_t)s*33792 + addr) = o;
}

// ---------------- main fused GEMM: emb @ [Wk^T | Wv^T | A2^T] ----------------
// 512 thr / 8 waves. wave = (sp = w>>2, ch = w&3): strips {2sp,2sp+1}, col-frags ch*8..ch*8+7 (+ frag32 all).
// Waves 0-3: A-staging (fp32->bf16, reg-pipelined one step ahead). Waves 4-7: B-staging via global_load_lds.
__launch_bounds__(512, 4)
__global__ void k_main(const float* __restrict__ emb, const unsigned char* __restrict__ bimg,
                       const int* __restrict__ mask, const float* __restrict__ consts,
                       float* __restrict__ rk_g, float* __restrict__ rv_g,
                       float* __restrict__ logits, unsigned char* __restrict__ ebf){
  __shared__ __align__(16) unsigned char smA[2][4096];
  __shared__ __align__(16) unsigned char smB[2][33792];
  __shared__ float part[4][4][16];
  __shared__ float rkbuf[64];
  const int tid = threadIdx.x;
  const int lane = tid & 63, wave = tid >> 6;
  const int sp = wave >> 2, ch = wave & 3;
  const int c = lane & 15, kg = lane >> 4;
  const int nb0 = blockIdx.x * 64;
  const bool isA = (wave < 4);
  const int anode = tid >> 2, aq = tid & 3;   // A-stage granule (waves 0-3)
  const int bw = wave - 4;

  float4 qb0, qb1;                             // in-flight A prefetch (next step to write)

  auto issueA = [&](int s){                    // load fp32 for step s into regs
    const float* ap = emb + (size_t)(nb0 + anode)*256 + s*32 + aq*8;
    qb0 = *(const float4*)ap;
    qb1 = *(const float4*)(ap + 4);
  };
  auto writeFrom = [&](float4 f0, float4 f1, int s, int buf){  // convert regs -> LDS (+ebf)
    uint4 o;
    o.x = (unsigned int)f2bf(f0.x) | ((unsigned int)f2bf(f0.y) << 16);
    o.y = (unsigned int)f2bf(f0.z) | ((unsigned int)f2bf(f0.w) << 16);
    o.z = (unsigned int)f2bf(f1.x) | ((unsigned int)f2bf(f1.y) << 16);
    o.w = (unsigned int)f2bf(f1.z) | ((unsigned int)f2bf(f1.w) << 16);
    *(uint4*)&smA[buf][anode*64 + ((aq ^ ((anode >> 1) & 3)) << 4)] = o;
    if (ebf) *(uint4*)(ebf + (size_t)(nb0 + anode)*512 + s*64 + aq*16) = o;
  };
  auto stageB = [&](int s, int buf){
    const unsigned char* bsrc = bimg + (size_t)s*33792;
    #pragma unroll
    for (int it = 0; it < 8; it++){
      int chunk = bw*8 + it;
      gload16(bsrc + chunk*1024 + lane*16, &smB[buf][chunk*1024]);
    }
    if (bw == 3) gload16(bsrc + 32*1024 + lane*16, &smB[buf][32768]);
  };

  f32x4 acc[2][9];
  #pragma unroll
  for (int st = 0; st < 2; st++)
    #pragma unroll
    for (int f = 0; f < 9; f++) acc[st][f] = (f32x4){0.f,0.f,0.f,0.f};

  // prologue: issue step0 AND step1 loads, then write step0 (one-time wait)
  if (isA){
    const float* ap0 = emb + (size_t)(nb0 + anode)*256 + aq*8;
    float4 qa0 = *(const float4*)ap0;
    float4 qa1 = *(const float4*)(ap0 + 4);
    issueA(1);
    writeFrom(qa0, qa1, 0, 0);
  } else {
    stageB(0, 0);
  }

  for (int s = 0; s < 8; s++){
    int cur = s & 1;
    __syncthreads();                     // smA/smB[cur] ready (issuing waves drained at barrier)
    if (s < 7){
      if (isA){
        writeFrom(qb0, qb1, s + 1, cur ^ 1);   // consume in-flight regs FIRST
        if (s + 2 <= 7) issueA(s + 2);         // then refill (fresh SSA values)
      } else {
        stageB(s + 1, cur ^ 1);
      }
    }
    bf16x8 af0 = *(const bf16x8*)&smA[cur][(2*sp+0)*1024 + c*64 + ((kg ^ ((c >> 1) & 3)) << 4)];
    bf16x8 af1 = *(const bf16x8*)&smA[cur][(2*sp+1)*1024 + c*64 + ((kg ^ ((c >> 1) & 3)) << 4)];
    #pragma unroll
    for (int f = 0; f < 9; f++){
      int cf = (f < 8) ? (ch*8 + f) : 32;
      bf16x8 bfv = *(const bf16x8*)&smB[cur][(((cf*16 + c)*64 + kg*16)) ^ ((c & 7) << 4)];
      acc[0][f] = __builtin_amdgcn_mfma_f32_16x16x32_bf16(af0, bfv, acc[0][f], 0, 0, 0);
      acc[1][f] = __builtin_amdgcn_mfma_f32_16x16x32_bf16(af1, bfv, acc[1][f], 0, 0, 0);
    }
  }

  // Epilogue: norms. ch0+ch1 = K-cols, ch2+ch3 = V-cols (frag32 excluded).
  #pragma unroll
  for (int st = 0; st < 2; st++){
    #pragma unroll
    for (int i = 0; i < 4; i++){
      float pp = 0.f;
      #pragma unroll
      for (int f = 0; f < 8; f++) pp += acc[st][f][i]*acc[st][f][i];
      #pragma unroll
      for (int m = 1; m < 16; m <<= 1) pp += __shfl_xor(pp, m);
      if (c == 0) part[ch][2*sp + st][kg*4 + i] = pp;
    }
  }
  __syncthreads();
  if (tid < 64){
    int gs = tid >> 4, r = tid & 15;
    float rk = fmaxf(sqrtf(part[0][gs][r] + part[1][gs][r]), 1e-12f);
    float rv = fmaxf(sqrtf(part[2][gs][r] + part[3][gs][r]), 1e-12f);
    rk_g[nb0 + tid] = rk; rv_g[nb0 + tid] = rv;
    rkbuf[tid] = rk;
  }
  __syncthreads();
  if (ch == 3 && c < 8){
    const float rs32 = 0.17677669529663688f;
    float cb = consts[c], ck = consts[8 + c];
    #pragma unroll
    for (int st = 0; st < 2; st++){
      #pragma unroll
      for (int i = 0; i < 4; i++){
        int nl = (2*sp + st)*16 + kg*4 + i;
        int n = nb0 + nl;
        float lg = (mask[n] == 0) ? ((acc[st][8][i] + cb)*rs32/rkbuf[nl] + ck*rs32) : NEGV;
        logits[(size_t)n*8 + c] = lg;
      }
    }
  }
}

// ---------------- logits softmax stats ([n][8] layout) ----------------
__global__ void k_lstats(const float* __restrict__ logits, float* __restrict__ lstat){
  int tid = threadIdx.x;
  float m[8], z[8];
  #pragma unroll
  for (int h = 0; h < 8; h++){ m[h] = -3.0e38f; z[h] = 0.f; }
  for (int n = blockIdx.x*256 + tid; n < NN; n += 128*256){
    float4 a = *(const float4*)(logits + (size_t)n*8);
    float4 b = *(const float4*)(logits + (size_t)n*8 + 4);
    float l[8] = {a.x,a.y,a.z,a.w,b.x,b.y,b.z,b.w};
    #pragma unroll
    for (int h = 0; h < 8; h++){
      float M = fmaxf(m[h], l[h]);
      z[h] = z[h]*expf(m[h]-M) + expf(l[h]-M);
      m[h] = M;
    }
  }
  #pragma unroll
  for (int s = 1; s < 64; s <<= 1){
    #pragma unroll
    for (int h = 0; h < 8; h++){
      float m2 = __shfl_xor(m[h], s), z2 = __shfl_xor(z[h], s);
      float M = fmaxf(m[h], m2);
      z[h] = z[h]*expf(m[h]-M) + z2*expf(m2-M);
      m[h] = M;
    }
  }
  __shared__ float sm[4][8], sz[4][8];
  int wave = tid >> 6, lane = tid & 63;
  if (lane == 0){
    #pragma unroll
    for (int h = 0; h < 8; h++){ sm[wave][h] = m[h]; sz[wave][h] = z[h]; }
  }
  __syncthreads();
  if (tid < 8){
    float M = sm[0][tid], Z = sz[0][tid];
    #pragma unroll
    for (int w = 1; w < 4; w++){
      float M2 = fmaxf(M, sm[w][tid]);
      Z = Z*expf(M-M2) + sz[w][tid]*expf(sm[w][tid]-M2);
      M = M2;
    }
    lstat[(blockIdx.x*8 + tid)*2] = M;
    lstat[(blockIdx.x*8 + tid)*2 + 1] = Z;
  }
}

__global__ void k_mz(const float* __restrict__ lstat, float* __restrict__ MZ){
  int t = threadIdx.x;
  int h = t >> 3, seg = t & 7;
  float m = -3.0e38f, z = 0.f;
  for (int k = 0; k < 16; k++){
    int b = seg*16 + k;
    float m2 = lstat[(b*8 + h)*2], z2 = lstat[(b*8 + h)*2 + 1];
    float M = fmaxf(m, m2); z = z*expf(m-M) + z2*expf(m2-M); m = M;
  }
  #pragma unroll
  for (int s = 1; s < 8; s <<= 1){
    float m2 = __shfl_xor(m, s), z2 = __shfl_xor(z, s);
    float M = fmaxf(m, m2); z = z*expf(m-M) + z2*expf(m2-M); m = M;
  }
  if (seg == 0){ MZ[h] = m; MZ[8+h] = z; }
}

// ---------------- weighted emb reduction ----------------
template<int BF>
__launch_bounds__(256)
__global__ void k_wsum(const void* __restrict__ embsrc, const float* __restrict__ logits,
                       const float* __restrict__ rv_g, const float* __restrict__ MZ,
                       float* __restrict__ upart, float* __restrict__ tpart){
  int tid = threadIdx.x, lane = tid & 63, wave = tid >> 6;
  int hl = lane & 31, h2 = lane >> 5;
  int gw = blockIdx.x*4 + wave;
  float Mh = MZ[hl & 7];
  float ua[8][8];
  #pragma unroll
  for (int h = 0; h < 8; h++)
    #pragma unroll
    for (int j = 0; j < 8; j++) ua[h][j] = 0.f;
  float tacc = 0.f;
  for (int p = gw; p < NN/2; p += 2048){
    int n = 2*p + h2;
    float e[8];
    if (BF){
      uint4 g = *(const uint4*)((const unsigned char*)embsrc + (size_t)n*512 + hl*16);
      e[0]=bf2f((unsigned short)(g.x&0xffff)); e[1]=bf2f((unsigned short)(g.x>>16));
      e[2]=bf2f((unsigned short)(g.y&0xffff)); e[3]=bf2f((unsigned short)(g.y>>16));
      e[4]=bf2f((unsigned short)(g.z&0xffff)); e[5]=bf2f((unsigned short)(g.z>>16));
      e[6]=bf2f((unsigned short)(g.w&0xffff)); e[7]=bf2f((unsigned short)(g.w>>16));
    } else {
      const float* ep = (const float*)embsrc + (size_t)n*256 + hl*8;
      float4 a = *(const float4*)ep, b = *(const float4*)(ep + 4);
      e[0]=a.x; e[1]=a.y; e[2]=a.z; e[3]=a.w; e[4]=b.x; e[5]=b.y; e[6]=b.z; e[7]=b.w;
    }
    float coef = 0.f;
    if (hl < 8) coef = expf(logits[(size_t)n*8 + hl] - Mh) / rv_g[n];
    tacc += coef;
    #pragma unroll
    for (int h = 0; h < 8; h++){
      float ch = __shfl(coef, h, 32);
      #pragma unroll
      for (int j = 0; j < 8; j++) ua[h][j] += ch * e[j];
    }
  }
  #pragma unroll
  for (int h = 0; h < 8; h++)
    #pragma unroll
    for (int j = 0; j < 8; j++) ua[h][j] += __shfl_xor(ua[h][j], 32);
  tacc += __shfl_xor(tacc, 32);
  __shared__ float ub[4][8][256];
  __shared__ float tb[4][8];
  if (h2 == 0){
    #pragma unroll
    for (int h = 0; h < 8; h++)
      #pragma unroll
      for (int j = 0; j < 8; j++) ub[wave][h][hl*8 + j] = ua[h][j];
    if (hl < 8) tb[wave][hl] = tacc;
  }
  __syncthreads();
  #pragma unroll
  for (int rep = 0; rep < 8; rep++){
    int idx = rep*256 + tid;
    int h = idx >> 8, j = idx & 255;
    upart[(size_t)blockIdx.x*2048 + h*256 + j] = ub[0][h][j]+ub[1][h][j]+ub[2][h][j]+ub[3][h][j];
  }
  if (tid < 8) tpart[blockIdx.x*8 + tid] = tb[0][tid]+tb[1][tid]+tb[2][tid]+tb[3][tid];
}

// upart[512][2048] reduce: 64 blocks = (h, jseg)
__global__ void k_ured(const float* __restrict__ upart, const float* __restrict__ tpart,
                       float* __restrict__ U, float* __restrict__ T){
  int b = blockIdx.x; int h = b >> 3, js = b & 7;
  int t = threadIdx.x; int j = js*32 + (t & 31); int br = t >> 5;
  float s = 0.f;
  for (int k = 0; k < 64; k++){
    int bb = k*8 + br;
    s += upart[(size_t)bb*2048 + h*256 + j];
  }
  __shared__ float sb[8][32];
  sb[br][t & 31] = s;
  __syncthreads();
  if (t < 32){
    float tot = 0.f;
    #pragma unroll
    for (int r = 0; r < 8; r++) tot += sb[r][t];
    U[h*256 + js*32 + t] = tot;
  }
  if (js == 0){
    float tp = 0.f;
    for (int i = t; i < 512; i += 256) tp += tpart[i*8 + h];
    #pragma unroll
    for (int m = 1; m < 64; m <<= 1) tp += __shfl_xor(tp, m);
    __shared__ float rr[4];
    if ((t & 63) == 0) rr[t >> 6] = tp;
    __syncthreads();
    if (t == 0) T[h] = rr[0]+rr[1]+rr[2]+rr[3];
  }
}

// ---------------- tiny attention/projection chain (wave-per-row, coalesced) ----------------
__global__ void k_attn(const float* __restrict__ U, const float* __restrict__ T,
                       const float* __restrict__ MZ,
                       const float* __restrict__ Wv, const float* __restrict__ bv,
                       const float* __restrict__ ipw, const float* __restrict__ ipb,
                       const float* __restrict__ opw, const float* __restrict__ opb,
                       const float* __restrict__ Wo, const float* __restrict__ bo,
                       const float* __restrict__ Wk, const float* __restrict__ bk,
                       float* __restrict__ kattn, float* __restrict__ kbout){
  int t = threadIdx.x, lane = t & 63, wave = t >> 6;
  __shared__ float u[8][256], sh2[8][256];
  __shared__ float a1[256], o1[256], o2s[256], af[256];
  __shared__ float red[4];
  #pragma unroll
  for (int h = 0; h < 8; h++) u[h][t] = U[h*256 + t];
  __syncthreads();
  for (int rr = 0; rr < 64; rr++){
    int e = wave*64 + rr;
    float acc8[8];
    #pragma unroll
    for (int h = 0; h < 8; h++) acc8[h] = 0.f;
    #pragma unroll
    for (int it = 0; it < 4; it++){
      float wv = Wv[e*256 + it*64 + lane];
      #pragma unroll
      for (int h = 0; h < 8; h++) acc8[h] += wv * u[h][it*64 + lane];
    }
    #pragma unroll
    for (int h = 0; h < 8; h++){
      #pragma unroll
      for (int m = 1; m < 64; m <<= 1) acc8[h] += __shfl_xor(acc8[h], m);
    }
    if (lane == 0){
      float bve = bv[e];
      #pragma unroll
      for (int h = 0; h < 8; h++) sh2[h][e] = (acc8[h] + bve*T[h]) / MZ[8+h];
    }
  }
  __syncthreads();
  for (int rr = 0; rr < 64; rr++){
    int e = wave*64 + rr;
    int h = e >> 5;
    float d = 0.f;
    #pragma unroll
    for (int it = 0; it < 4; it++) d += ipw[(512 + e)*256 + it*64 + lane] * sh2[h][it*64 + lane];
    #pragma unroll
    for (int m = 1; m < 64; m <<= 1) d += __shfl_xor(d, m);
    if (lane == 0) a1[e] = d + ipb[512 + e];
  }
  __syncthreads();
  for (int rr = 0; rr < 64; rr++){
    int e = wave*64 + rr;
    float d = 0.f;
    #pragma unroll
    for (int it = 0; it < 4; it++) d += opw[e*256 + it*64 + lane] * a1[it*64 + lane];
    #pragma unroll
    for (int m = 1; m < 64; m <<= 1) d += __shfl_xor(d, m);
    if (lane == 0) o1[e] = d + opb[e];
  }
  __syncthreads();
  for (int rr = 0; rr < 64; rr++){
    int e = wave*64 + rr;
    float d = 0.f;
    #pragma unroll
    for (int it = 0; it < 4; it++) d += Wo[e*256 + it*64 + lane] * o1[it*64 + lane];
    #pragma unroll
    for (int m = 1; m < 64; m <<= 1) d += __shfl_xor(d, m);
    if (lane == 0) o2s[e] = d + bo[e];
  }
  __syncthreads();
  {
    float sq = o2s[t]*o2s[t];
    #pragma unroll
    for (int m = 1; m < 64; m <<= 1) sq += __shfl_xor(sq, m);
    if (lane == 0) red[wave] = sq;
    __syncthreads();
    float nrm = fmaxf(sqrtf(red[0]+red[1]+red[2]+red[3]), 1e-12f);
    af[t] = o2s[t] / nrm;
  }
  __syncthreads();
  {
    float a = 0.f;
    for (int e = 0; e < 256; e++) a += af[e]*Wk[e*256 + t];
    kattn[t] = a;
  }
  {
    float cc = af[t]*bk[t];
    #pragma unroll
    for (int m = 1; m < 64; m <<= 1) cc += __shfl_xor(cc, m);
    __syncthreads();
    if (lane == 0) red[wave] = cc;
    __syncthreads();
    if (t == 0) kbout[0] = red[0]+red[1]+red[2]+red[3];
  }
}

// ---------------- scores + online softmax stats ----------------
template<int BF>
__launch_bounds__(256)
__global__ void k_scores(const void* __restrict__ embsrc, const float* __restrict__ rk_g,
                         const int* __restrict__ mask, const float* __restrict__ kattn,
                         const float* __restrict__ kbp, float* __restrict__ scores,
                         float* __restrict__ p3stat){
  int tid = threadIdx.x, lane = tid & 63, wave = tid >> 6;
  int hl = lane & 31, h2 = lane >> 5;
  __shared__ float ka[256];
  ka[tid] = kattn[tid];
  __syncthreads();
  float kb = kbp[0];
  float kv[8];
  #pragma unroll
  for (int j = 0; j < 8; j++) kv[j] = ka[hl*8 + j];
  int gw = blockIdx.x*4 + wave;
  float m = -3.0e38f, z = 0.f;
  for (int p = gw; p < NN/2; p += 2048){
    int n = 2*p + h2;
    float d;
    if (BF){
      uint4 g = *(const uint4*)((const unsigned char*)embsrc + (size_t)n*512 + hl*16);
      d  = bf2f((unsigned short)(g.x&0xffff))*kv[0] + bf2f((unsigned short)(g.x>>16))*kv[1];
      d += bf2f((unsigned short)(g.y&0xffff))*kv[2] + bf2f((unsigned short)(g.y>>16))*kv[3];
      d += bf2f((unsigned short)(g.z&0xffff))*kv[4] + bf2f((unsigned short)(g.z>>16))*kv[5];
      d += bf2f((unsigned short)(g.w&0xffff))*kv[6] + bf2f((unsigned short)(g.w>>16))*kv[7];
    } else {
      const float* ep = (const float*)embsrc + (size_t)n*256 + hl*8;
      float4 a = *(const float4*)ep, b = *(const float4*)(ep + 4);
      d = a.x*kv[0]+a.y*kv[1]+a.z*kv[2]+a.w*kv[3]+b.x*kv[4]+b.y*kv[5]+b.z*kv[6]+b.w*kv[7];
    }
    #pragma unroll
    for (int s = 1; s < 32; s <<= 1) d += __shfl_xor(d, s);
    if (hl == 0){
      float sc = (mask[n] == 0) ? ((d + kb) / rk_g[n]) : NEGV;
      scores[n] = sc;
      float M = fmaxf(m, sc);
      z = z*expf(m - M) + expf(sc - M);
      m = M;
    }
  }
  float m2 = __shfl_xor(m, 32), z2 = __shfl_xor(z, 32);
  float M = fmaxf(m, m2); z = z*expf(m-M) + z2*expf(m2-M); m = M;
  __shared__ float rm[4], rz[4];
  if (lane == 0){ rm[wave] = m; rz[wave] = z; }
  __syncthreads();
  if (tid == 0){
    float Mx = rm[0], Z = rz[0];
    for (int w = 1; w < 4; w++){
      float M2 = fmaxf(Mx, rm[w]);
      Z = Z*expf(Mx - M2) + rz[w]*expf(rm[w] - M2);
      Mx = M2;
    }
    p3stat[blockIdx.x*2] = Mx; p3stat[blockIdx.x*2+1] = Z;
  }
}

__global__ void k_mz3(const float* __restrict__ p3stat, float* __restrict__ MZ3){
  int t = threadIdx.x;
  float m = p3stat[t*2], z = p3stat[t*2+1];
  {
    float m2 = p3stat[(t+256)*2], z2 = p3stat[(t+256)*2+1];
    float M = fmaxf(m, m2); z = z*expf(m-M) + z2*expf(m2-M); m = M;
  }
  #pragma unroll
  for (int mm = 1; mm < 64; mm <<= 1){
    float ms = __shfl_xor(m, mm), zs = __shfl_xor(z, mm);
    float Mx = fmaxf(m, ms); z = z*expf(m-Mx) + zs*expf(ms-Mx); m = Mx;
  }
  __shared__ float rm[4], rz[4];
  if ((t&63)==0){ rm[t>>6]=m; rz[t>>6]=z; }
  __syncthreads();
  if (t==0){
    float M=rm[0], Z=rz[0];
    for (int w=1; w<4; w++){ float Mx=fmaxf(M,rm[w]); Z=Z*expf(M-Mx)+rz[w]*expf(rm[w]-Mx); M=Mx; }
    MZ3[0]=M; MZ3[1]=Z;
  }
}

__global__ void k_probs(const float* __restrict__ scores, const float* __restrict__ MZ3,
                        float* __restrict__ out){
  float M = MZ3[0], iZ = 1.0f / MZ3[1];
  for (int n = blockIdx.x*256 + threadIdx.x; n < NN; n += 512*256)
    out[n] = expf(scores[n] - M) * iZ;
}

// ---------------- launcher ----------------
extern "C" void kernel_launch(void* const* d_in, const int* in_sizes, int n_in,
                              void* d_out, int out_size, void* d_ws, size_t ws_size,
                              hipStream_t stream){
  (void)in_sizes; (void)n_in; (void)out_size;
  const float* ctx = (const float*)d_in[0];
  const float* emb = (const float*)d_in[1];
  const int*   mask= (const int*)d_in[2];
  const float* Wc  = (const float*)d_in[3];
  const float* bc  = (const float*)d_in[4];
  const float* Wk  = (const float*)d_in[5];
  const float* bk  = (const float*)d_in[6];
  const float* Wv  = (const float*)d_in[7];
  const float* bv  = (const float*)d_in[8];
  const float* ipw = (const float*)d_in[9];
  const float* ipb = (const float*)d_in[10];
  const float* opw = (const float*)d_in[11];
  const float* opb = (const float*)d_in[12];
  const float* Wo  = (const float*)d_in[13];
  const float* bo  = (const float*)d_in[14];
  float* out = (float*)d_out;
  char* ws = (char*)d_ws;

  float* rk     = (float*)(ws + OFF_RK);
  float* rv     = (float*)(ws + OFF_RV);
  float* logits = (float*)(ws + OFF_LOGITS);
  float* scores = (float*)(ws + OFF_SCORES);
  float* A2     = (float*)(ws + OFF_A2);
  float* consts = (float*)(ws + OFF_CONSTS);
  unsigned char* bimg = (unsigned char*)(ws + OFF_BIMG);
  float* lstat  = (float*)(ws + OFF_LSTAT);
  float* MZ     = (float*)(ws + OFF_MZ);
  float* kattn  = (float*)(ws + OFF_KATTN);
  float* kb     = (float*)(ws + OFF_KB);
  float* upart  = (float*)(ws + OFF_UPART);
  float* tpart  = (float*)(ws + OFF_TPART);
  float* U      = (float*)(ws + OFF_U);
  float* T      = (float*)(ws + OFF_T);
  float* p3stat = (float*)(ws + OFF_P3STAT);
  float* MZ3    = (float*)(ws + OFF_MZ3);

  const bool bf = ws_size >= WS_NEED_BF;
  unsigned char* ebf = bf ? (unsigned char*)(ws + OFF_EMBBF) : nullptr;

  k_prep  <<<1,   256, 0, stream>>>(ctx, Wc, bc, ipw, ipb, Wk, bk, A2, consts);
  k_bimg  <<<66,  256, 0, stream>>>(Wk, Wv, A2, bimg);
  k_main  <<<3125,512, 0, stream>>>(emb, bimg, mask, consts, rk, rv, logits, ebf);
  k_lstats<<<128, 256, 0, stream>>>(logits, lstat);
  k_mz    <<<1,   64,  0, stream>>>(lstat, MZ);
  if (bf) k_wsum<1><<<512, 256, 0, stream>>>(ebf, logits, rv, MZ, upart, tpart);
  else    k_wsum<0><<<512, 256, 0, stream>>>(emb, logits, rv, MZ, upart, tpart);
  k_ured  <<<64,  256, 0, stream>>>(upart, tpart, U, T);
  k_attn  <<<1,   256, 0, stream>>>(U, T, MZ, Wv, bv, ipw, ipb, opw, opb, Wo, bo, Wk, bk, kattn, kb);
  if (bf) k_scores<1><<<512, 256, 0, stream>>>(ebf, rk, mask, kattn, kb, scores, p3stat);
  else    k_scores<0><<<512, 256, 0, stream>>>(emb, rk, mask, kattn, kb, scores, p3stat);
  k_mz3   <<<1,   256, 0, stream>>>(p3stat, MZ3);
  k_probs <<<512, 256, 0, stream>>>(scores, MZ3, out);
}

// Round 5
// 746.034 us; speedup vs baseline: 1.1200x; 1.1200x over previous
//
#include <hip/hip_runtime.h>

#define NN 200000
#define NEGV -1000000000.0f

typedef __attribute__((ext_vector_type(8))) short bf16x8;
typedef __attribute__((ext_vector_type(4))) float f32x4;

__device__ __forceinline__ float bf2f(unsigned short u){
  unsigned int x = ((unsigned int)u) << 16;
  return __builtin_bit_cast(float, x);
}
__device__ __forceinline__ unsigned short f2bf(float f){
  unsigned int x = __builtin_bit_cast(unsigned int, f);
  x += 0x7fffu + ((x >> 16) & 1u);
  return (unsigned short)(x >> 16);
}
__device__ __forceinline__ void gload16(const void* g, void* l){
  __builtin_amdgcn_global_load_lds((const __attribute__((address_space(1))) unsigned int*)g,
                                   (__attribute__((address_space(3))) unsigned int*)l, 16, 0, 0);
}

// ---------------- workspace layout (bytes) ----------------
static constexpr size_t OFF_RK     = 0;
static constexpr size_t OFF_RV     = 800256;
static constexpr size_t OFF_LOGITS = 1600512;   // [n][8] f32
static constexpr size_t OFF_SCORES = 8000512;
static constexpr size_t OFF_A2     = 8802816;
static constexpr size_t OFF_CONSTS = 8811008;
static constexpr size_t OFF_BIMG   = 8811264;   // 8*528*64
static constexpr size_t OFF_LSTAT  = 9081600;   // 128*8*2 f32
static constexpr size_t OFF_MZ     = 9089792;
static constexpr size_t OFF_KATTN  = 9089856;
static constexpr size_t OFF_KB     = 9090880;
static constexpr size_t OFF_UPART  = 9090944;   // 512*2048 f32
static constexpr size_t OFF_TPART  = 13285248;  // 512*8 f32
static constexpr size_t OFF_U      = 13301632;
static constexpr size_t OFF_T      = 13309824;
static constexpr size_t OFF_P3STAT = 13309888;  // 512*2
static constexpr size_t OFF_MZ3    = 13313984;
static constexpr size_t OFF_EMBBF  = 13314048;  // N*256 bf16 = 102.4MB
static constexpr size_t WS_NEED_BF = OFF_EMBBF + (size_t)NN*512;

// ---------------- fused prep: query -> q2 -> A -> A2/consts (1 block) ----------------
__global__ void k_prep(const float* __restrict__ ctx, const float* __restrict__ Wc,
                       const float* __restrict__ bc, const float* __restrict__ ipw,
                       const float* __restrict__ ipb, const float* __restrict__ Wk,
                       const float* __restrict__ bk, float* __restrict__ A2,
                       float* __restrict__ consts){
  int t = threadIdx.x, lane = t & 63, wave = t >> 6;
  __shared__ float ctxs[768], querys[256], q2s[256], AHs[256];
  __shared__ float red2[4], red3[4];
  #pragma unroll
  for (int r = 0; r < 3; r++) ctxs[r*256 + t] = ctx[r*256 + t];
  __syncthreads();
  for (int rr = 0; rr < 64; rr++){
    int r = wave*64 + rr;
    float d = 0.f;
    #pragma unroll
    for (int it = 0; it < 12; it++) d += ctxs[it*64 + lane] * Wc[r*768 + it*64 + lane];
    #pragma unroll
    for (int m = 1; m < 64; m <<= 1) d += __shfl_xor(d, m);
    if (lane == 0) querys[r] = d + bc[r];
  }
  __syncthreads();
  for (int rr = 0; rr < 64; rr++){
    int r = wave*64 + rr;
    float d = 0.f;
    #pragma unroll
    for (int it = 0; it < 4; it++) d += querys[it*64 + lane] * ipw[r*256 + it*64 + lane];
    #pragma unroll
    for (int m = 1; m < 64; m <<= 1) d += __shfl_xor(d, m);
    if (lane == 0) q2s[r] = d + ipb[r];
  }
  __syncthreads();
  for (int h = 0; h < 8; h++){
    float a = 0.f;
    #pragma unroll
    for (int d = 0; d < 32; d++) a += q2s[h*32 + d] * ipw[(256 + h*32 + d)*256 + t];
    __syncthreads();              // prior AHs readers done
    AHs[t] = a;
    float v = (t < 32) ? q2s[h*32 + t] * ipb[256 + h*32 + t] : 0.f;
    #pragma unroll
    for (int m = 1; m < 64; m <<= 1) v += __shfl_xor(v, m);
    if (lane == 0) red2[wave] = v;
    __syncthreads();              // AHs + red2 visible
    if (t == 0) consts[8 + h] = red2[0] + red2[1] + red2[2] + red2[3];
    float a2 = 0.f;
    for (int e = 0; e < 256; e++) a2 += AHs[e] * Wk[e*256 + t];
    A2[h*256 + t] = a2;
    float cc = AHs[t] * bk[t];
    #pragma unroll
    for (int m = 1; m < 64; m <<= 1) cc += __shfl_xor(cc, m);
    if (lane == 0) red3[wave] = cc;
    __syncthreads();
    if (t == 0) consts[h] = red3[0] + red3[1] + red3[2] + red3[3];
  }
}

// Pre-swizzled bf16 B image: per k-step s (8), col (528: Wk|Wv|A2+pad), kg (4):
// 16B granule at s*33792 + ((col*64 + kg*16) ^ ((col&7)<<4))
__global__ void k_bimg(const float* __restrict__ Wk, const float* __restrict__ Wv,
                       const float* __restrict__ A2, unsigned char* __restrict__ bimg){
  int g = blockIdx.x*256 + threadIdx.x;
  if (g >= 8*528*4) return;
  int s = g / (528*4);
  int rem = g % (528*4);
  int col = rem >> 2, kg = rem & 3;
  int j0 = s*32 + kg*8;
  const float* src = nullptr;
  if (col < 256) src = Wk + col*256 + j0;
  else if (col < 512) src = Wv + (col-256)*256 + j0;
  else if (col < 520) src = A2 + (col-512)*256 + j0;
  unsigned short u[8];
  #pragma unroll
  for (int i = 0; i < 8; i++) u[i] = src ? f2bf(src[i]) : (unsigned short)0;
  uint4 o;
  o.x = (unsigned int)u[0] | ((unsigned int)u[1] << 16);
  o.y = (unsigned int)u[2] | ((unsigned int)u[3] << 16);
  o.z = (unsigned int)u[4] | ((unsigned int)u[5] << 16);
  o.w = (unsigned int)u[6] | ((unsigned int)u[7] << 16);
  unsigned int addr = (unsigned int)((col*64 + kg*16) ^ ((col & 7) << 4));
  *(uint4*)(bimg + (size_t)s*33792 + addr) = o;
}

// ---------------- main fused GEMM: emb @ [Wk^T | Wv^T | A2^T] ----------------
// 512 thr / 8 waves. wave = (sp = w>>2, ch = w&3): strips {2sp,2sp+1}, col-frags ch*8..ch*8+7 (+ frag32 all).
// Waves 0-3: A-staging (fp32->bf16, reg-pipelined). Waves 4-7: B-staging via global_load_lds.
// ebf written ONCE at the end with per-instruction-contiguous full-line stores
// (per-k-step 64B scatter caused 4x HBM write amplification — r4 post-mortem).
__launch_bounds__(512, 4)
__global__ void k_main(const float* __restrict__ emb, const unsigned char* __restrict__ bimg,
                       const int* __restrict__ mask, const float* __restrict__ consts,
                       float* __restrict__ rk_g, float* __restrict__ rv_g,
                       float* __restrict__ logits, unsigned char* __restrict__ ebf){
  __shared__ __align__(16) unsigned char smA[2][4096];
  __shared__ __align__(16) unsigned char smB[2][33792];
  __shared__ float part[4][4][16];
  __shared__ float rkbuf[64];
  const int tid = threadIdx.x;
  const int lane = tid & 63, wave = tid >> 6;
  const int sp = wave >> 2, ch = wave & 3;
  const int c = lane & 15, kg = lane >> 4;
  const int nb0 = blockIdx.x * 64;
  const bool isA = (wave < 4);
  const int anode = tid >> 2, aq = tid & 3;   // A-stage granule (waves 0-3)
  const int bw = wave - 4;

  float4 qb0, qb1;                             // in-flight A prefetch (next step to write)

  auto issueA = [&](int s){                    // load fp32 for step s into regs
    const float* ap = emb + (size_t)(nb0 + anode)*256 + s*32 + aq*8;
    qb0 = *(const float4*)ap;
    qb1 = *(const float4*)(ap + 4);
  };
  auto writeFrom = [&](float4 f0, float4 f1, int buf){  // convert regs -> LDS
    uint4 o;
    o.x = (unsigned int)f2bf(f0.x) | ((unsigned int)f2bf(f0.y) << 16);
    o.y = (unsigned int)f2bf(f0.z) | ((unsigned int)f2bf(f0.w) << 16);
    o.z = (unsigned int)f2bf(f1.x) | ((unsigned int)f2bf(f1.y) << 16);
    o.w = (unsigned int)f2bf(f1.z) | ((unsigned int)f2bf(f1.w) << 16);
    *(uint4*)&smA[buf][anode*64 + ((aq ^ ((anode >> 1) & 3)) << 4)] = o;
  };
  auto stageB = [&](int s, int buf){
    const unsigned char* bsrc = bimg + (size_t)s*33792;
    #pragma unroll
    for (int it = 0; it < 8; it++){
      int chunk = bw*8 + it;
      gload16(bsrc + chunk*1024 + lane*16, &smB[buf][chunk*1024]);
    }
    if (bw == 3) gload16(bsrc + 32*1024 + lane*16, &smB[buf][32768]);
  };

  f32x4 acc[2][9];
  #pragma unroll
  for (int st = 0; st < 2; st++)
    #pragma unroll
    for (int f = 0; f < 9; f++) acc[st][f] = (f32x4){0.f,0.f,0.f,0.f};

  // prologue: issue step0 AND step1 loads, then write step0 (one-time wait)
  if (isA){
    const float* ap0 = emb + (size_t)(nb0 + anode)*256 + aq*8;
    float4 qa0 = *(const float4*)ap0;
    float4 qa1 = *(const float4*)(ap0 + 4);
    issueA(1);
    writeFrom(qa0, qa1, 0);
  } else {
    stageB(0, 0);
  }

  for (int s = 0; s < 8; s++){
    int cur = s & 1;
    __syncthreads();                     // smA/smB[cur] ready (issuing waves drained at barrier)
    if (s < 7){
      if (isA){
        writeFrom(qb0, qb1, cur ^ 1);    // consume in-flight regs FIRST
        if (s + 2 <= 7) issueA(s + 2);   // then refill (fresh SSA values)
      } else {
        stageB(s + 1, cur ^ 1);
      }
    }
    bf16x8 af0 = *(const bf16x8*)&smA[cur][(2*sp+0)*1024 + c*64 + ((kg ^ ((c >> 1) & 3)) << 4)];
    bf16x8 af1 = *(const bf16x8*)&smA[cur][(2*sp+1)*1024 + c*64 + ((kg ^ ((c >> 1) & 3)) << 4)];
    #pragma unroll
    for (int f = 0; f < 9; f++){
      int cf = (f < 8) ? (ch*8 + f) : 32;
      bf16x8 bfv = *(const bf16x8*)&smB[cur][(((cf*16 + c)*64 + kg*16)) ^ ((c & 7) << 4)];
      acc[0][f] = __builtin_amdgcn_mfma_f32_16x16x32_bf16(af0, bfv, acc[0][f], 0, 0, 0);
      acc[1][f] = __builtin_amdgcn_mfma_f32_16x16x32_bf16(af1, bfv, acc[1][f], 0, 0, 0);
    }
  }

  // Coalesced ebf writeout: 2048 16B-granules, granule gi = it*512+tid ->
  // ebf[nb0*512 + gi*16]; each wave-instruction writes a contiguous 8KB run.
  // emb rows are L2/L3-hot (just read by the K-loop).
  if (ebf){
    #pragma unroll
    for (int it = 0; it < 4; it++){
      int gi = it*512 + tid;
      int node = gi >> 5, q = gi & 31;
      const float* src = emb + (size_t)(nb0 + node)*256 + q*8;
      float4 a = *(const float4*)src;
      float4 b = *(const float4*)(src + 4);
      uint4 o;
      o.x = (unsigned int)f2bf(a.x) | ((unsigned int)f2bf(a.y) << 16);
      o.y = (unsigned int)f2bf(a.z) | ((unsigned int)f2bf(a.w) << 16);
      o.z = (unsigned int)f2bf(b.x) | ((unsigned int)f2bf(b.y) << 16);
      o.w = (unsigned int)f2bf(b.z) | ((unsigned int)f2bf(b.w) << 16);
      *(uint4*)(ebf + (size_t)nb0*512 + (size_t)gi*16) = o;
    }
  }

  // Epilogue: norms. ch0+ch1 = K-cols, ch2+ch3 = V-cols (frag32 excluded).
  #pragma unroll
  for (int st = 0; st < 2; st++){
    #pragma unroll
    for (int i = 0; i < 4; i++){
      float pp = 0.f;
      #pragma unroll
      for (int f = 0; f < 8; f++) pp += acc[st][f][i]*acc[st][f][i];
      #pragma unroll
      for (int m = 1; m < 16; m <<= 1) pp += __shfl_xor(pp, m);
      if (c == 0) part[ch][2*sp + st][kg*4 + i] = pp;
    }
  }
  __syncthreads();
  if (tid < 64){
    int gs = tid >> 4, r = tid & 15;
    float rk = fmaxf(sqrtf(part[0][gs][r] + part[1][gs][r]), 1e-12f);
    float rv = fmaxf(sqrtf(part[2][gs][r] + part[3][gs][r]), 1e-12f);
    rk_g[nb0 + tid] = rk; rv_g[nb0 + tid] = rv;
    rkbuf[tid] = rk;
  }
  __syncthreads();
  if (ch == 3 && c < 8){
    const float rs32 = 0.17677669529663688f;
    float cb = consts[c], ck = consts[8 + c];
    #pragma unroll
    for (int st = 0; st < 2; st++){
      #pragma unroll
      for (int i = 0; i < 4; i++){
        int nl = (2*sp + st)*16 + kg*4 + i;
        int n = nb0 + nl;
        float lg = (mask[n] == 0) ? ((acc[st][8][i] + cb)*rs32/rkbuf[nl] + ck*rs32) : NEGV;
        logits[(size_t)n*8 + c] = lg;
      }
    }
  }
}

// ---------------- logits softmax stats ([n][8] layout) ----------------
__global__ void k_lstats(const float* __restrict__ logits, float* __restrict__ lstat){
  int tid = threadIdx.x;
  float m[8], z[8];
  #pragma unroll
  for (int h = 0; h < 8; h++){ m[h] = -3.0e38f; z[h] = 0.f; }
  for (int n = blockIdx.x*256 + tid; n < NN; n += 128*256){
    float4 a = *(const float4*)(logits + (size_t)n*8);
    float4 b = *(const float4*)(logits + (size_t)n*8 + 4);
    float l[8] = {a.x,a.y,a.z,a.w,b.x,b.y,b.z,b.w};
    #pragma unroll
    for (int h = 0; h < 8; h++){
      float M = fmaxf(m[h], l[h]);
      z[h] = z[h]*expf(m[h]-M) + expf(l[h]-M);
      m[h] = M;
    }
  }
  #pragma unroll
  for (int s = 1; s < 64; s <<= 1){
    #pragma unroll
    for (int h = 0; h < 8; h++){
      float m2 = __shfl_xor(m[h], s), z2 = __shfl_xor(z[h], s);
      float M = fmaxf(m[h], m2);
      z[h] = z[h]*expf(m[h]-M) + z2*expf(m2-M);
      m[h] = M;
    }
  }
  __shared__ float sm[4][8], sz[4][8];
  int wave = tid >> 6, lane = tid & 63;
  if (lane == 0){
    #pragma unroll
    for (int h = 0; h < 8; h++){ sm[wave][h] = m[h]; sz[wave][h] = z[h]; }
  }
  __syncthreads();
  if (tid < 8){
    float M = sm[0][tid], Z = sz[0][tid];
    #pragma unroll
    for (int w = 1; w < 4; w++){
      float M2 = fmaxf(M, sm[w][tid]);
      Z = Z*expf(M-M2) + sz[w][tid]*expf(sm[w][tid]-M2);
      M = M2;
    }
    lstat[(blockIdx.x*8 + tid)*2] = M;
    lstat[(blockIdx.x*8 + tid)*2 + 1] = Z;
  }
}

__global__ void k_mz(const float* __restrict__ lstat, float* __restrict__ MZ){
  int t = threadIdx.x;
  int h = t >> 3, seg = t & 7;
  float m = -3.0e38f, z = 0.f;
  for (int k = 0; k < 16; k++){
    int b = seg*16 + k;
    float m2 = lstat[(b*8 + h)*2], z2 = lstat[(b*8 + h)*2 + 1];
    float M = fmaxf(m, m2); z = z*expf(m-M) + z2*expf(m2-M); m = M;
  }
  #pragma unroll
  for (int s = 1; s < 8; s <<= 1){
    float m2 = __shfl_xor(m, s), z2 = __shfl_xor(z, s);
    float M = fmaxf(m, m2); z = z*expf(m-M) + z2*expf(m2-M); m = M;
  }
  if (seg == 0){ MZ[h] = m; MZ[8+h] = z; }
}

// ---------------- weighted emb reduction ----------------
template<int BF>
__launch_bounds__(256)
__global__ void k_wsum(const void* __restrict__ embsrc, const float* __restrict__ logits,
                       const float* __restrict__ rv_g, const float* __restrict__ MZ,
                       float* __restrict__ upart, float* __restrict__ tpart){
  int tid = threadIdx.x, lane = tid & 63, wave = tid >> 6;
  int hl = lane & 31, h2 = lane >> 5;
  int gw = blockIdx.x*4 + wave;
  float Mh = MZ[hl & 7];
  float ua[8][8];
  #pragma unroll
  for (int h = 0; h < 8; h++)
    #pragma unroll
    for (int j = 0; j < 8; j++) ua[h][j] = 0.f;
  float tacc = 0.f;
  for (int p = gw; p < NN/2; p += 2048){
    int n = 2*p + h2;
    float e[8];
    if (BF){
      uint4 g = *(const uint4*)((const unsigned char*)embsrc + (size_t)n*512 + hl*16);
      e[0]=bf2f((unsigned short)(g.x&0xffff)); e[1]=bf2f((unsigned short)(g.x>>16));
      e[2]=bf2f((unsigned short)(g.y&0xffff)); e[3]=bf2f((unsigned short)(g.y>>16));
      e[4]=bf2f((unsigned short)(g.z&0xffff)); e[5]=bf2f((unsigned short)(g.z>>16));
      e[6]=bf2f((unsigned short)(g.w&0xffff)); e[7]=bf2f((unsigned short)(g.w>>16));
    } else {
      const float* ep = (const float*)embsrc + (size_t)n*256 + hl*8;
      float4 a = *(const float4*)ep, b = *(const float4*)(ep + 4);
      e[0]=a.x; e[1]=a.y; e[2]=a.z; e[3]=a.w; e[4]=b.x; e[5]=b.y; e[6]=b.z; e[7]=b.w;
    }
    float coef = 0.f;
    if (hl < 8) coef = expf(logits[(size_t)n*8 + hl] - Mh) / rv_g[n];
    tacc += coef;
    #pragma unroll
    for (int h = 0; h < 8; h++){
      float ch = __shfl(coef, h, 32);
      #pragma unroll
      for (int j = 0; j < 8; j++) ua[h][j] += ch * e[j];
    }
  }
  #pragma unroll
  for (int h = 0; h < 8; h++)
    #pragma unroll
    for (int j = 0; j < 8; j++) ua[h][j] += __shfl_xor(ua[h][j], 32);
  tacc += __shfl_xor(tacc, 32);
  __shared__ float ub[4][8][256];
  __shared__ float tb[4][8];
  if (h2 == 0){
    #pragma unroll
    for (int h = 0; h < 8; h++)
      #pragma unroll
      for (int j = 0; j < 8; j++) ub[wave][h][hl*8 + j] = ua[h][j];
    if (hl < 8) tb[wave][hl] = tacc;
  }
  __syncthreads();
  #pragma unroll
  for (int rep = 0; rep < 8; rep++){
    int idx = rep*256 + tid;
    int h = idx >> 8, j = idx & 255;
    upart[(size_t)blockIdx.x*2048 + h*256 + j] = ub[0][h][j]+ub[1][h][j]+ub[2][h][j]+ub[3][h][j];
  }
  if (tid < 8) tpart[blockIdx.x*8 + tid] = tb[0][tid]+tb[1][tid]+tb[2][tid]+tb[3][tid];
}

// upart[512][2048] reduce: 64 blocks = (h, jseg)
__global__ void k_ured(const float* __restrict__ upart, const float* __restrict__ tpart,
                       float* __restrict__ U, float* __restrict__ T){
  int b = blockIdx.x; int h = b >> 3, js = b & 7;
  int t = threadIdx.x; int j = js*32 + (t & 31); int br = t >> 5;
  float s = 0.f;
  for (int k = 0; k < 64; k++){
    int bb = k*8 + br;
    s += upart[(size_t)bb*2048 + h*256 + j];
  }
  __shared__ float sb[8][32];
  sb[br][t & 31] = s;
  __syncthreads();
  if (t < 32){
    float tot = 0.f;
    #pragma unroll
    for (int r = 0; r < 8; r++) tot += sb[r][t];
    U[h*256 + js*32 + t] = tot;
  }
  if (js == 0){
    float tp = 0.f;
    for (int i = t; i < 512; i += 256) tp += tpart[i*8 + h];
    #pragma unroll
    for (int m = 1; m < 64; m <<= 1) tp += __shfl_xor(tp, m);
    __shared__ float rr[4];
    if ((t & 63) == 0) rr[t >> 6] = tp;
    __syncthreads();
    if (t == 0) T[h] = rr[0]+rr[1]+rr[2]+rr[3];
  }
}

// ---------------- tiny attention/projection chain (wave-per-row, coalesced) ----------------
__global__ void k_attn(const float* __restrict__ U, const float* __restrict__ T,
                       const float* __restrict__ MZ,
                       const float* __restrict__ Wv, const float* __restrict__ bv,
                       const float* __restrict__ ipw, const float* __restrict__ ipb,
                       const float* __restrict__ opw, const float* __restrict__ opb,
                       const float* __restrict__ Wo, const float* __restrict__ bo,
                       const float* __restrict__ Wk, const float* __restrict__ bk,
                       float* __restrict__ kattn, float* __restrict__ kbout){
  int t = threadIdx.x, lane = t & 63, wave = t >> 6;
  __shared__ float u[8][256], sh2[8][256];
  __shared__ float a1[256], o1[256], o2s[256], af[256];
  __shared__ float red[4];
  #pragma unroll
  for (int h = 0; h < 8; h++) u[h][t] = U[h*256 + t];
  __syncthreads();
  for (int rr = 0; rr < 64; rr++){
    int e = wave*64 + rr;
    float acc8[8];
    #pragma unroll
    for (int h = 0; h < 8; h++) acc8[h] = 0.f;
    #pragma unroll
    for (int it = 0; it < 4; it++){
      float wv = Wv[e*256 + it*64 + lane];
      #pragma unroll
      for (int h = 0; h < 8; h++) acc8[h] += wv * u[h][it*64 + lane];
    }
    #pragma unroll
    for (int h = 0; h < 8; h++){
      #pragma unroll
      for (int m = 1; m < 64; m <<= 1) acc8[h] += __shfl_xor(acc8[h], m);
    }
    if (lane == 0){
      float bve = bv[e];
      #pragma unroll
      for (int h = 0; h < 8; h++) sh2[h][e] = (acc8[h] + bve*T[h]) / MZ[8+h];
    }
  }
  __syncthreads();
  for (int rr = 0; rr < 64; rr++){
    int e = wave*64 + rr;
    int h = e >> 5;
    float d = 0.f;
    #pragma unroll
    for (int it = 0; it < 4; it++) d += ipw[(512 + e)*256 + it*64 + lane] * sh2[h][it*64 + lane];
    #pragma unroll
    for (int m = 1; m < 64; m <<= 1) d += __shfl_xor(d, m);
    if (lane == 0) a1[e] = d + ipb[512 + e];
  }
  __syncthreads();
  for (int rr = 0; rr < 64; rr++){
    int e = wave*64 + rr;
    float d = 0.f;
    #pragma unroll
    for (int it = 0; it < 4; it++) d += opw[e*256 + it*64 + lane] * a1[it*64 + lane];
    #pragma unroll
    for (int m = 1; m < 64; m <<= 1) d += __shfl_xor(d, m);
    if (lane == 0) o1[e] = d + opb[e];
  }
  __syncthreads();
  for (int rr = 0; rr < 64; rr++){
    int e = wave*64 + rr;
    float d = 0.f;
    #pragma unroll
    for (int it = 0; it < 4; it++) d += Wo[e*256 + it*64 + lane] * o1[it*64 + lane];
    #pragma unroll
    for (int m = 1; m < 64; m <<= 1) d += __shfl_xor(d, m);
    if (lane == 0) o2s[e] = d + bo[e];
  }
  __syncthreads();
  {
    float sq = o2s[t]*o2s[t];
    #pragma unroll
    for (int m = 1; m < 64; m <<= 1) sq += __shfl_xor(sq, m);
    if (lane == 0) red[wave] = sq;
    __syncthreads();
    float nrm = fmaxf(sqrtf(red[0]+red[1]+red[2]+red[3]), 1e-12f);
    af[t] = o2s[t] / nrm;
  }
  __syncthreads();
  {
    float a = 0.f;
    for (int e = 0; e < 256; e++) a += af[e]*Wk[e*256 + t];
    kattn[t] = a;
  }
  {
    float cc = af[t]*bk[t];
    #pragma unroll
    for (int m = 1; m < 64; m <<= 1) cc += __shfl_xor(cc, m);
    __syncthreads();
    if (lane == 0) red[wave] = cc;
    __syncthreads();
    if (t == 0) kbout[0] = red[0]+red[1]+red[2]+red[3];
  }
}

// ---------------- scores + online softmax stats ----------------
template<int BF>
__launch_bounds__(256)
__global__ void k_scores(const void* __restrict__ embsrc, const float* __restrict__ rk_g,
                         const int* __restrict__ mask, const float* __restrict__ kattn,
                         const float* __restrict__ kbp, float* __restrict__ scores,
                         float* __restrict__ p3stat){
  int tid = threadIdx.x, lane = tid & 63, wave = tid >> 6;
  int hl = lane & 31, h2 = lane >> 5;
  __shared__ float ka[256];
  ka[tid] = kattn[tid];
  __syncthreads();
  float kb = kbp[0];
  float kv[8];
  #pragma unroll
  for (int j = 0; j < 8; j++) kv[j] = ka[hl*8 + j];
  int gw = blockIdx.x*4 + wave;
  float m = -3.0e38f, z = 0.f;
  for (int p = gw; p < NN/2; p += 2048){
    int n = 2*p + h2;
    float d;
    if (BF){
      uint4 g = *(const uint4*)((const unsigned char*)embsrc + (size_t)n*512 + hl*16);
      d  = bf2f((unsigned short)(g.x&0xffff))*kv[0] + bf2f((unsigned short)(g.x>>16))*kv[1];
      d += bf2f((unsigned short)(g.y&0xffff))*kv[2] + bf2f((unsigned short)(g.y>>16))*kv[3];
      d += bf2f((unsigned short)(g.z&0xffff))*kv[4] + bf2f((unsigned short)(g.z>>16))*kv[5];
      d += bf2f((unsigned short)(g.w&0xffff))*kv[6] + bf2f((unsigned short)(g.w>>16))*kv[7];
    } else {
      const float* ep = (const float*)embsrc + (size_t)n*256 + hl*8;
      float4 a = *(const float4*)ep, b = *(const float4*)(ep + 4);
      d = a.x*kv[0]+a.y*kv[1]+a.z*kv[2]+a.w*kv[3]+b.x*kv[4]+b.y*kv[5]+b.z*kv[6]+b.w*kv[7];
    }
    #pragma unroll
    for (int s = 1; s < 32; s <<= 1) d += __shfl_xor(d, s);
    if (hl == 0){
      float sc = (mask[n] == 0) ? ((d + kb) / rk_g[n]) : NEGV;
      scores[n] = sc;
      float M = fmaxf(m, sc);
      z = z*expf(m - M) + expf(sc - M);
      m = M;
    }
  }
  float m2 = __shfl_xor(m, 32), z2 = __shfl_xor(z, 32);
  float M = fmaxf(m, m2); z = z*expf(m-M) + z2*expf(m2-M); m = M;
  __shared__ float rm[4], rz[4];
  if (lane == 0){ rm[wave] = m; rz[wave] = z; }
  __syncthreads();
  if (tid == 0){
    float Mx = rm[0], Z = rz[0];
    for (int w = 1; w < 4; w++){
      float M2 = fmaxf(Mx, rm[w]);
      Z = Z*expf(Mx - M2) + rz[w]*expf(rm[w] - M2);
      Mx = M2;
    }
    p3stat[blockIdx.x*2] = Mx; p3stat[blockIdx.x*2+1] = Z;
  }
}

__global__ void k_mz3(const float* __restrict__ p3stat, float* __restrict__ MZ3){
  int t = threadIdx.x;
  float m = p3stat[t*2], z = p3stat[t*2+1];
  {
    float m2 = p3stat[(t+256)*2], z2 = p3stat[(t+256)*2+1];
    float M = fmaxf(m, m2); z = z*expf(m-M) + z2*expf(m2-M); m = M;
  }
  #pragma unroll
  for (int mm = 1; mm < 64; mm <<= 1){
    float ms = __shfl_xor(m, mm), zs = __shfl_xor(z, mm);
    float Mx = fmaxf(m, ms); z = z*expf(m-Mx) + zs*expf(ms-Mx); m = Mx;
  }
  __shared__ float rm[4], rz[4];
  if ((t&63)==0){ rm[t>>6]=m; rz[t>>6]=z; }
  __syncthreads();
  if (t==0){
    float M=rm[0], Z=rz[0];
    for (int w=1; w<4; w++){ float Mx=fmaxf(M,rm[w]); Z=Z*expf(M-Mx)+rz[w]*expf(rm[w]-Mx); M=Mx; }
    MZ3[0]=M; MZ3[1]=Z;
  }
}

__global__ void k_probs(const float* __restrict__ scores, const float* __restrict__ MZ3,
                        float* __restrict__ out){
  float M = MZ3[0], iZ = 1.0f / MZ3[1];
  for (int n = blockIdx.x*256 + threadIdx.x; n < NN; n += 512*256)
    out[n] = expf(scores[n] - M) * iZ;
}

// ---------------- launcher ----------------
extern "C" void kernel_launch(void* const* d_in, const int* in_sizes, int n_in,
                              void* d_out, int out_size, void* d_ws, size_t ws_size,
                              hipStream_t stream){
  (void)in_sizes; (void)n_in; (void)out_size;
  const float* ctx = (const float*)d_in[0];
  const float* emb = (const float*)d_in[1];
  const int*   mask= (const int*)d_in[2];
  const float* Wc  = (const float*)d_in[3];
  const float* bc  = (const float*)d_in[4];
  const float* Wk  = (const float*)d_in[5];
  const float* bk  = (const float*)d_in[6];
  const float* Wv  = (const float*)d_in[7];
  const float* bv  = (const float*)d_in[8];
  const float* ipw = (const float*)d_in[9];
  const float* ipb = (const float*)d_in[10];
  const float* opw = (const float*)d_in[11];
  const float* opb = (const float*)d_in[12];
  const float* Wo  = (const float*)d_in[13];
  const float* bo  = (const float*)d_in[14];
  float* out = (float*)d_out;
  char* ws = (char*)d_ws;

  float* rk     = (float*)(ws + OFF_RK);
  float* rv     = (float*)(ws + OFF_RV);
  float* logits = (float*)(ws + OFF_LOGITS);
  float* scores = (float*)(ws + OFF_SCORES);
  float* A2     = (float*)(ws + OFF_A2);
  float* consts = (float*)(ws + OFF_CONSTS);
  unsigned char* bimg = (unsigned char*)(ws + OFF_BIMG);
  float* lstat  = (float*)(ws + OFF_LSTAT);
  float* MZ     = (float*)(ws + OFF_MZ);
  float* kattn  = (float*)(ws + OFF_KATTN);
  float* kb     = (float*)(ws + OFF_KB);
  float* upart  = (float*)(ws + OFF_UPART);
  float* tpart  = (float*)(ws + OFF_TPART);
  float* U      = (float*)(ws + OFF_U);
  float* T      = (float*)(ws + OFF_T);
  float* p3stat = (float*)(ws + OFF_P3STAT);
  float* MZ3    = (float*)(ws + OFF_MZ3);

  const bool bf = ws_size >= WS_NEED_BF;
  unsigned char* ebf = bf ? (unsigned char*)(ws + OFF_EMBBF) : nullptr;

  k_prep  <<<1,   256, 0, stream>>>(ctx, Wc, bc, ipw, ipb, Wk, bk, A2, consts);
  k_bimg  <<<66,  256, 0, stream>>>(Wk, Wv, A2, bimg);
  k_main  <<<3125,512, 0, stream>>>(emb, bimg, mask, consts, rk, rv, logits, ebf);
  k_lstats<<<128, 256, 0, stream>>>(logits, lstat);
  k_mz    <<<1,   64,  0, stream>>>(lstat, MZ);
  if (bf) k_wsum<1><<<512, 256, 0, stream>>>(ebf, logits, rv, MZ, upart, tpart);
  else    k_wsum<0><<<512, 256, 0, stream>>>(emb, logits, rv, MZ, upart, tpart);
  k_ured  <<<64,  256, 0, stream>>>(upart, tpart, U, T);
  k_attn  <<<1,   256, 0, stream>>>(U, T, MZ, Wv, bv, ipw, ipb, opw, opb, Wo, bo, Wk, bk, kattn, kb);
  if (bf) k_scores<1><<<512, 256, 0, stream>>>(ebf, rk, mask, kattn, kb, scores, p3stat);
  else    k_scores<0><<<512, 256, 0, stream>>>(emb, rk, mask, kattn, kb, scores, p3stat);
  k_mz3   <<<1,   256, 0, stream>>>(p3stat, MZ3);
  k_probs <<<512, 256, 0, stream>>>(scores, MZ3, out);
}

// Round 6
// 324.093 us; speedup vs baseline: 2.5781x; 2.3019x over previous
//
#include <hip/hip_runtime.h>

#define NN 200000
#define NEGV -1000000000.0f

typedef __attribute__((ext_vector_type(8))) short bf16x8;
typedef __attribute__((ext_vector_type(4))) float f32x4;

__device__ __forceinline__ float bf2f(unsigned short u){
  unsigned int x = ((unsigned int)u) << 16;
  return __builtin_bit_cast(float, x);
}
__device__ __forceinline__ unsigned short f2bf(float f){
  unsigned int x = __builtin_bit_cast(unsigned int, f);
  x += 0x7fffu + ((x >> 16) & 1u);
  return (unsigned short)(x >> 16);
}
__device__ __forceinline__ void gload16(const void* g, void* l){
  __builtin_amdgcn_global_load_lds((const __attribute__((address_space(1))) unsigned int*)g,
                                   (__attribute__((address_space(3))) unsigned int*)l, 16, 0, 0);
}

// ---------------- workspace layout (bytes) ----------------
static constexpr size_t OFF_RK     = 0;
static constexpr size_t OFF_RV     = 800256;
static constexpr size_t OFF_LOGITS = 1600512;   // [n][8] f32
static constexpr size_t OFF_SCORES = 8000512;
static constexpr size_t OFF_QUERY  = 8800768;   // 256 f32
static constexpr size_t OFF_Q2     = 8801792;   // 256 f32
static constexpr size_t OFF_A2     = 8802816;   // 8*256 f32
static constexpr size_t OFF_CONSTS = 8811008;   // cb[8], ck[8]
static constexpr size_t OFF_BIMG   = 8811264;   // 8*528*64
static constexpr size_t OFF_LSTAT  = 9081600;   // 128*8*2 f32
static constexpr size_t OFF_MZ     = 9089792;
static constexpr size_t OFF_KATTN  = 9089856;
static constexpr size_t OFF_KB     = 9090880;
static constexpr size_t OFF_UPART  = 9090944;   // 512*2048 f32 (time-shared scratch)
static constexpr size_t OFF_TPART  = 13285248;  // 512*8 f32
static constexpr size_t OFF_U      = 13301632;
static constexpr size_t OFF_T      = 13309824;
static constexpr size_t OFF_P3STAT = 13309888;  // 512*2
static constexpr size_t OFF_MZ3    = 13313984;
static constexpr size_t OFF_EMBBF  = 13314048;  // N*256 bf16 = 102.4MB (step-major permuted)
static constexpr size_t WS_NEED_BF = OFF_EMBBF + (size_t)NN*512;
// time-shared inside UPART region:
//   prep phase (before wsum):  AH at +32768 (8KB), A2p at +65536 (64KB)
//   attn phase (after ured):   sh2g +0 (8KB), a1g +8192, o1g +9216, o2g +10240, kp +11264 (8KB)

// ================= prep chain (multi-block, latency-spread) =================
// query[r] = ctx . Wc[r,:] + bc[r]     grid 32 x 256
__global__ void k_prep1(const float* __restrict__ ctx, const float* __restrict__ Wc,
                        const float* __restrict__ bc, float* __restrict__ query){
  int tid = threadIdx.x, lane = tid & 63, wave = tid >> 6;
  float4 c0 = *(const float4*)(ctx + lane*4);
  float4 c1 = *(const float4*)(ctx + 256 + lane*4);
  float4 c2 = *(const float4*)(ctx + 512 + lane*4);
  #pragma unroll
  for (int rr = 0; rr < 2; rr++){
    int r = blockIdx.x*8 + wave*2 + rr;
    float4 w0 = *(const float4*)(Wc + (size_t)r*768 + lane*4);
    float4 w1 = *(const float4*)(Wc + (size_t)r*768 + 256 + lane*4);
    float4 w2 = *(const float4*)(Wc + (size_t)r*768 + 512 + lane*4);
    float d = w0.x*c0.x + w0.y*c0.y + w0.z*c0.z + w0.w*c0.w
            + w1.x*c1.x + w1.y*c1.y + w1.z*c1.z + w1.w*c1.w
            + w2.x*c2.x + w2.y*c2.y + w2.z*c2.z + w2.w*c2.w;
    #pragma unroll
    for (int m = 1; m < 64; m <<= 1) d += __shfl_xor(d, m);
    if (lane == 0) query[r] = d + bc[r];
  }
}

// q2[r] = query . ipw[r,:] + ipb[r]    grid 32 x 256
__global__ void k_prep2(const float* __restrict__ ipw, const float* __restrict__ ipb,
                        const float* __restrict__ query, float* __restrict__ q2){
  int tid = threadIdx.x, lane = tid & 63, wave = tid >> 6;
  float4 x4 = *(const float4*)(query + lane*4);
  #pragma unroll
  for (int rr = 0; rr < 2; rr++){
    int r = blockIdx.x*8 + wave*2 + rr;
    float4 w4 = *(const float4*)(ipw + (size_t)r*256 + lane*4);
    float d = w4.x*x4.x + w4.y*x4.y + w4.z*x4.z + w4.w*x4.w;
    #pragma unroll
    for (int m = 1; m < 64; m <<= 1) d += __shfl_xor(d, m);
    if (lane == 0) q2[r] = d + ipb[r];
  }
}

// AH[h][t] + consts[8+h]    grid 8 x 256
__global__ void k_prep3(const float* __restrict__ ipw, const float* __restrict__ ipb,
                        const float* __restrict__ q2, float* __restrict__ AH,
                        float* __restrict__ consts){
  int h = blockIdx.x, t = threadIdx.x;
  __shared__ float qs[32];
  if (t < 32) qs[t] = q2[h*32 + t];
  __syncthreads();
  float a = 0.f;
  #pragma unroll
  for (int d = 0; d < 32; d++) a += qs[d] * ipw[(size_t)(256 + h*32 + d)*256 + t];
  AH[h*256 + t] = a;
  if (t == 0){
    float ck = 0.f;
    for (int d = 0; d < 32; d++) ck += qs[d] * ipb[256 + h*32 + d];
    consts[8 + h] = ck;
  }
}

// A2 partials: grid 64 = (h, seg) x 256 thr
__global__ void k_prep4(const float* __restrict__ Wk, const float* __restrict__ AH,
                        float* __restrict__ A2p){
  int b = blockIdx.x, h = b >> 3, seg = b & 7, t = threadIdx.x;
  __shared__ float as[32];
  if (t < 32) as[t] = AH[h*256 + seg*32 + t];
  __syncthreads();
  float acc = 0.f;
  #pragma unroll
  for (int i = 0; i < 32; i++) acc += as[i] * Wk[(size_t)(seg*32 + i)*256 + t];
  A2p[(size_t)b*256 + t] = acc;
}

// A2 finalize + consts[h]: grid 8 x 256
__global__ void k_prep5(const float* __restrict__ A2p, const float* __restrict__ AH,
                        const float* __restrict__ bk, float* __restrict__ A2,
                        float* __restrict__ consts){
  int h = blockIdx.x, t = threadIdx.x, lane = t & 63, wave = t >> 6;
  float s = 0.f;
  #pragma unroll
  for (int seg = 0; seg < 8; seg++) s += A2p[(size_t)(h*8 + seg)*256 + t];
  A2[h*256 + t] = s;
  float cc = AH[h*256 + t] * bk[t];
  #pragma unroll
  for (int m = 1; m < 64; m <<= 1) cc += __shfl_xor(cc, m);
  __shared__ float red[4];
  if (lane == 0) red[wave] = cc;
  __syncthreads();
  if (t == 0) consts[h] = red[0] + red[1] + red[2] + red[3];
}

// Pre-swizzled bf16 B image
__global__ void k_bimg(const float* __restrict__ Wk, const float* __restrict__ Wv,
                       const float* __restrict__ A2, unsigned char* __restrict__ bimg){
  int g = blockIdx.x*256 + threadIdx.x;
  if (g >= 8*528*4) return;
  int s = g / (528*4);
  int rem = g % (528*4);
  int col = rem >> 2, kg = rem & 3;
  int j0 = s*32 + kg*8;
  const float* src = nullptr;
  if (col < 256) src = Wk + col*256 + j0;
  else if (col < 512) src = Wv + (col-256)*256 + j0;
  else if (col < 520) src = A2 + (col-512)*256 + j0;
  unsigned short u[8];
  #pragma unroll
  for (int i = 0; i < 8; i++) u[i] = src ? f2bf(src[i]) : (unsigned short)0;
  uint4 o;
  o.x = (unsigned int)u[0] | ((unsigned int)u[1] << 16);
  o.y = (unsigned int)u[2] | ((unsigned int)u[3] << 16);
  o.z = (unsigned int)u[4] | ((unsigned int)u[5] << 16);
  o.w = (unsigned int)u[6] | ((unsigned int)u[7] << 16);
  unsigned int addr = (unsigned int)((col*64 + kg*16) ^ ((col & 7) << 4));
  *(uint4*)(bimg + (size_t)s*33792 + addr) = o;
}

// ---------------- main fused GEMM: emb @ [Wk^T | Wv^T | A2^T] ----------------
// ebf written per-step in STEP-MAJOR layout: blk*32768 + s*4096 + tid*16
// -> each store instruction covers 4KB contiguous (full lines, no RMW).
__launch_bounds__(512, 4)
__global__ void k_main(const float* __restrict__ emb, const unsigned char* __restrict__ bimg,
                       const int* __restrict__ mask, const float* __restrict__ consts,
                       float* __restrict__ rk_g, float* __restrict__ rv_g,
                       float* __restrict__ logits, unsigned char* __restrict__ ebf){
  __shared__ __align__(16) unsigned char smA[2][4096];
  __shared__ __align__(16) unsigned char smB[2][33792];
  __shared__ float part[4][4][16];
  __shared__ float rkbuf[64];
  const int tid = threadIdx.x;
  const int lane = tid & 63, wave = tid >> 6;
  const int sp = wave >> 2, ch = wave & 3;
  const int c = lane & 15, kg = lane >> 4;
  const int nb0 = blockIdx.x * 64;
  const bool isA = (wave < 4);
  const int anode = tid >> 2, aq = tid & 3;
  const int bw = wave - 4;

  float4 qb0, qb1;

  auto issueA = [&](int s){
    const float* ap = emb + (size_t)(nb0 + anode)*256 + s*32 + aq*8;
    qb0 = *(const float4*)ap;
    qb1 = *(const float4*)(ap + 4);
  };
  auto writeFrom = [&](float4 f0, float4 f1, int s, int buf){
    uint4 o;
    o.x = (unsigned int)f2bf(f0.x) | ((unsigned int)f2bf(f0.y) << 16);
    o.y = (unsigned int)f2bf(f0.z) | ((unsigned int)f2bf(f0.w) << 16);
    o.z = (unsigned int)f2bf(f1.x) | ((unsigned int)f2bf(f1.y) << 16);
    o.w = (unsigned int)f2bf(f1.z) | ((unsigned int)f2bf(f1.w) << 16);
    *(uint4*)&smA[buf][anode*64 + ((aq ^ ((anode >> 1) & 3)) << 4)] = o;
    if (ebf) *(uint4*)(ebf + (size_t)blockIdx.x*32768 + (size_t)s*4096 + (size_t)tid*16) = o;
  };
  auto stageB = [&](int s, int buf){
    const unsigned char* bsrc = bimg + (size_t)s*33792;
    #pragma unroll
    for (int it = 0; it < 8; it++){
      int chunk = bw*8 + it;
      gload16(bsrc + chunk*1024 + lane*16, &smB[buf][chunk*1024]);
    }
    if (bw == 3) gload16(bsrc + 32*1024 + lane*16, &smB[buf][32768]);
  };

  f32x4 acc[2][9];
  #pragma unroll
  for (int st = 0; st < 2; st++)
    #pragma unroll
    for (int f = 0; f < 9; f++) acc[st][f] = (f32x4){0.f,0.f,0.f,0.f};

  if (isA){
    const float* ap0 = emb + (size_t)(nb0 + anode)*256 + aq*8;
    float4 qa0 = *(const float4*)ap0;
    float4 qa1 = *(const float4*)(ap0 + 4);
    issueA(1);
    writeFrom(qa0, qa1, 0, 0);
  } else {
    stageB(0, 0);
  }

  for (int s = 0; s < 8; s++){
    int cur = s & 1;
    __syncthreads();
    if (s < 7){
      if (isA){
        writeFrom(qb0, qb1, s + 1, cur ^ 1);   // consume in-flight regs FIRST
        if (s + 2 <= 7) issueA(s + 2);         // then refill
      } else {
        stageB(s + 1, cur ^ 1);
      }
    }
    bf16x8 af0 = *(const bf16x8*)&smA[cur][(2*sp+0)*1024 + c*64 + ((kg ^ ((c >> 1) & 3)) << 4)];
    bf16x8 af1 = *(const bf16x8*)&smA[cur][(2*sp+1)*1024 + c*64 + ((kg ^ ((c >> 1) & 3)) << 4)];
    #pragma unroll
    for (int f = 0; f < 9; f++){
      int cf = (f < 8) ? (ch*8 + f) : 32;
      bf16x8 bfv = *(const bf16x8*)&smB[cur][(((cf*16 + c)*64 + kg*16)) ^ ((c & 7) << 4)];
      acc[0][f] = __builtin_amdgcn_mfma_f32_16x16x32_bf16(af0, bfv, acc[0][f], 0, 0, 0);
      acc[1][f] = __builtin_amdgcn_mfma_f32_16x16x32_bf16(af1, bfv, acc[1][f], 0, 0, 0);
    }
  }

  #pragma unroll
  for (int st = 0; st < 2; st++){
    #pragma unroll
    for (int i = 0; i < 4; i++){
      float pp = 0.f;
      #pragma unroll
      for (int f = 0; f < 8; f++) pp += acc[st][f][i]*acc[st][f][i];
      #pragma unroll
      for (int m = 1; m < 16; m <<= 1) pp += __shfl_xor(pp, m);
      if (c == 0) part[ch][2*sp + st][kg*4 + i] = pp;
    }
  }
  __syncthreads();
  if (tid < 64){
    int gs = tid >> 4, r = tid & 15;
    float rk = fmaxf(sqrtf(part[0][gs][r] + part[1][gs][r]), 1e-12f);
    float rv = fmaxf(sqrtf(part[2][gs][r] + part[3][gs][r]), 1e-12f);
    rk_g[nb0 + tid] = rk; rv_g[nb0 + tid] = rv;
    rkbuf[tid] = rk;
  }
  __syncthreads();
  if (ch == 3 && c < 8){
    const float rs32 = 0.17677669529663688f;
    float cb = consts[c], ck = consts[8 + c];
    #pragma unroll
    for (int st = 0; st < 2; st++){
      #pragma unroll
      for (int i = 0; i < 4; i++){
        int nl = (2*sp + st)*16 + kg*4 + i;
        int n = nb0 + nl;
        float lg = (mask[n] == 0) ? ((acc[st][8][i] + cb)*rs32/rkbuf[nl] + ck*rs32) : NEGV;
        logits[(size_t)n*8 + c] = lg;
      }
    }
  }
}

// ---------------- logits softmax stats ----------------
__global__ void k_lstats(const float* __restrict__ logits, float* __restrict__ lstat){
  int tid = threadIdx.x;
  float m[8], z[8];
  #pragma unroll
  for (int h = 0; h < 8; h++){ m[h] = -3.0e38f; z[h] = 0.f; }
  for (int n = blockIdx.x*256 + tid; n < NN; n += 128*256){
    float4 a = *(const float4*)(logits + (size_t)n*8);
    float4 b = *(const float4*)(logits + (size_t)n*8 + 4);
    float l[8] = {a.x,a.y,a.z,a.w,b.x,b.y,b.z,b.w};
    #pragma unroll
    for (int h = 0; h < 8; h++){
      float M = fmaxf(m[h], l[h]);
      z[h] = z[h]*expf(m[h]-M) + expf(l[h]-M);
      m[h] = M;
    }
  }
  #pragma unroll
  for (int s = 1; s < 64; s <<= 1){
    #pragma unroll
    for (int h = 0; h < 8; h++){
      float m2 = __shfl_xor(m[h], s), z2 = __shfl_xor(z[h], s);
      float M = fmaxf(m[h], m2);
      z[h] = z[h]*expf(m[h]-M) + z2*expf(m2-M);
      m[h] = M;
    }
  }
  __shared__ float sm[4][8], sz[4][8];
  int wave = tid >> 6, lane = tid & 63;
  if (lane == 0){
    #pragma unroll
    for (int h = 0; h < 8; h++){ sm[wave][h] = m[h]; sz[wave][h] = z[h]; }
  }
  __syncthreads();
  if (tid < 8){
    float M = sm[0][tid], Z = sz[0][tid];
    #pragma unroll
    for (int w = 1; w < 4; w++){
      float M2 = fmaxf(M, sm[w][tid]);
      Z = Z*expf(M-M2) + sz[w][tid]*expf(sm[w][tid]-M2);
      M = M2;
    }
    lstat[(blockIdx.x*8 + tid)*2] = M;
    lstat[(blockIdx.x*8 + tid)*2 + 1] = Z;
  }
}

__global__ void k_mz(const float* __restrict__ lstat, float* __restrict__ MZ){
  int t = threadIdx.x;
  int h = t >> 3, seg = t & 7;
  float m = -3.0e38f, z = 0.f;
  for (int k = 0; k < 16; k++){
    int b = seg*16 + k;
    float m2 = lstat[(b*8 + h)*2], z2 = lstat[(b*8 + h)*2 + 1];
    float M = fmaxf(m, m2); z = z*expf(m-M) + z2*expf(m2-M); m = M;
  }
  #pragma unroll
  for (int s = 1; s < 8; s <<= 1){
    float m2 = __shfl_xor(m, s), z2 = __shfl_xor(z, s);
    float M = fmaxf(m, m2); z = z*expf(m-M) + z2*expf(m2-M); m = M;
  }
  if (seg == 0){ MZ[h] = m; MZ[8+h] = z; }
}

// ---------------- weighted emb reduction (reads step-major ebf) ----------------
template<int BF>
__launch_bounds__(256)
__global__ void k_wsum(const void* __restrict__ embsrc, const float* __restrict__ logits,
                       const float* __restrict__ rv_g, const float* __restrict__ MZ,
                       float* __restrict__ upart, float* __restrict__ tpart){
  int tid = threadIdx.x, lane = tid & 63, wave = tid >> 6;
  int hl = lane & 31, h2 = lane >> 5;
  int gw = blockIdx.x*4 + wave;
  float Mh = MZ[hl & 7];
  float ua[8][8];
  #pragma unroll
  for (int h = 0; h < 8; h++)
    #pragma unroll
    for (int j = 0; j < 8; j++) ua[h][j] = 0.f;
  float tacc = 0.f;
  for (int p = gw; p < NN/2; p += 2048){
    int n = 2*p + h2;
    float e[8];
    if (BF){
      size_t addr = (size_t)(n >> 6)*32768 + (size_t)(hl >> 2)*4096
                  + (size_t)(n & 63)*64 + (size_t)(hl & 3)*16;
      uint4 g = *(const uint4*)((const unsigned char*)embsrc + addr);
      e[0]=bf2f((unsigned short)(g.x&0xffff)); e[1]=bf2f((unsigned short)(g.x>>16));
      e[2]=bf2f((unsigned short)(g.y&0xffff)); e[3]=bf2f((unsigned short)(g.y>>16));
      e[4]=bf2f((unsigned short)(g.z&0xffff)); e[5]=bf2f((unsigned short)(g.z>>16));
      e[6]=bf2f((unsigned short)(g.w&0xffff)); e[7]=bf2f((unsigned short)(g.w>>16));
    } else {
      const float* ep = (const float*)embsrc + (size_t)n*256 + hl*8;
      float4 a = *(const float4*)ep, b = *(const float4*)(ep + 4);
      e[0]=a.x; e[1]=a.y; e[2]=a.z; e[3]=a.w; e[4]=b.x; e[5]=b.y; e[6]=b.z; e[7]=b.w;
    }
    float coef = 0.f;
    if (hl < 8) coef = expf(logits[(size_t)n*8 + hl] - Mh) / rv_g[n];
    tacc += coef;
    #pragma unroll
    for (int h = 0; h < 8; h++){
      float ch = __shfl(coef, h, 32);
      #pragma unroll
      for (int j = 0; j < 8; j++) ua[h][j] += ch * e[j];
    }
  }
  #pragma unroll
  for (int h = 0; h < 8; h++)
    #pragma unroll
    for (int j = 0; j < 8; j++) ua[h][j] += __shfl_xor(ua[h][j], 32);
  tacc += __shfl_xor(tacc, 32);
  __shared__ float ub[4][8][256];
  __shared__ float tb[4][8];
  if (h2 == 0){
    #pragma unroll
    for (int h = 0; h < 8; h++)
      #pragma unroll
      for (int j = 0; j < 8; j++) ub[wave][h][hl*8 + j] = ua[h][j];
    if (hl < 8) tb[wave][hl] = tacc;
  }
  __syncthreads();
  #pragma unroll
  for (int rep = 0; rep < 8; rep++){
    int idx = rep*256 + tid;
    int h = idx >> 8, j = idx & 255;
    upart[(size_t)blockIdx.x*2048 + h*256 + j] = ub[0][h][j]+ub[1][h][j]+ub[2][h][j]+ub[3][h][j];
  }
  if (tid < 8) tpart[blockIdx.x*8 + tid] = tb[0][tid]+tb[1][tid]+tb[2][tid]+tb[3][tid];
}

__global__ void k_ured(const float* __restrict__ upart, const float* __restrict__ tpart,
                       float* __restrict__ U, float* __restrict__ T){
  int b = blockIdx.x; int h = b >> 3, js = b & 7;
  int t = threadIdx.x; int j = js*32 + (t & 31); int br = t >> 5;
  float s = 0.f;
  for (int k = 0; k < 64; k++){
    int bb = k*8 + br;
    s += upart[(size_t)bb*2048 + h*256 + j];
  }
  __shared__ float sb[8][32];
  sb[br][t & 31] = s;
  __syncthreads();
  if (t < 32){
    float tot = 0.f;
    #pragma unroll
    for (int r = 0; r < 8; r++) tot += sb[r][t];
    U[h*256 + js*32 + t] = tot;
  }
  if (js == 0){
    float tp = 0.f;
    for (int i = t; i < 512; i += 256) tp += tpart[i*8 + h];
    #pragma unroll
    for (int m = 1; m < 64; m <<= 1) tp += __shfl_xor(tp, m);
    __shared__ float rr[4];
    if ((t & 63) == 0) rr[t >> 6] = tp;
    __syncthreads();
    if (t == 0) T[h] = rr[0]+rr[1]+rr[2]+rr[3];
  }
}

// ================= attn chain (multi-block, latency-spread) =================
// sh2g[h][r] = (Wv[r]·u_h + bv[r]*T[h]) / Z[h]    grid 32 x 256
__global__ void k_att1(const float* __restrict__ U, const float* __restrict__ T,
                       const float* __restrict__ MZ, const float* __restrict__ Wv,
                       const float* __restrict__ bv, float* __restrict__ sh2g){
  int tid = threadIdx.x, lane = tid & 63, wave = tid >> 6;
  float4 uh[8];
  #pragma unroll
  for (int h = 0; h < 8; h++) uh[h] = *(const float4*)(U + h*256 + lane*4);
  #pragma unroll
  for (int rr = 0; rr < 2; rr++){
    int r = blockIdx.x*8 + wave*2 + rr;
    float4 w4 = *(const float4*)(Wv + (size_t)r*256 + lane*4);
    float acc[8];
    #pragma unroll
    for (int h = 0; h < 8; h++)
      acc[h] = w4.x*uh[h].x + w4.y*uh[h].y + w4.z*uh[h].z + w4.w*uh[h].w;
    #pragma unroll
    for (int m = 1; m < 64; m <<= 1)
      #pragma unroll
      for (int h = 0; h < 8; h++) acc[h] += __shfl_xor(acc[h], m);
    if (lane == 0){
      float bvr = bv[r];
      #pragma unroll
      for (int h = 0; h < 8; h++) sh2g[h*256 + r] = (acc[h] + bvr*T[h]) / MZ[8+h];
    }
  }
}

// a1[r] = ipw[512+r]·sh2g[r>>5] + ipb[512+r]    grid 32 x 256
__global__ void k_att2(const float* __restrict__ ipw, const float* __restrict__ ipb,
                       const float* __restrict__ sh2g, float* __restrict__ a1g){
  int tid = threadIdx.x, lane = tid & 63, wave = tid >> 6;
  #pragma unroll
  for (int rr = 0; rr < 2; rr++){
    int r = blockIdx.x*8 + wave*2 + rr;
    int h = r >> 5;
    float4 x4 = *(const float4*)(sh2g + h*256 + lane*4);
    float4 w4 = *(const float4*)(ipw + (size_t)(512 + r)*256 + lane*4);
    float d = w4.x*x4.x + w4.y*x4.y + w4.z*x4.z + w4.w*x4.w;
    #pragma unroll
    for (int m = 1; m < 64; m <<= 1) d += __shfl_xor(d, m);
    if (lane == 0) a1g[r] = d + ipb[512 + r];
  }
}

// generic y[r] = W[r]·x + b[r]    grid 32 x 256
__global__ void k_matvec(const float* __restrict__ W, const float* __restrict__ b,
                         const float* __restrict__ x, float* __restrict__ y){
  int tid = threadIdx.x, lane = tid & 63, wave = tid >> 6;
  float4 x4 = *(const float4*)(x + lane*4);
  #pragma unroll
  for (int rr = 0; rr < 2; rr++){
    int r = blockIdx.x*8 + wave*2 + rr;
    float4 w4 = *(const float4*)(W + (size_t)r*256 + lane*4);
    float d = w4.x*x4.x + w4.y*x4.y + w4.z*x4.z + w4.w*x4.w;
    #pragma unroll
    for (int m = 1; m < 64; m <<= 1) d += __shfl_xor(d, m);
    if (lane == 0) y[r] = d + b[r];
  }
}

// kraw partials: kp[b][t] = sum_{e in b*32..+31} o2[e]*Wk[e*256+t]   grid 8 x 256
__global__ void k_att5(const float* __restrict__ Wk, const float* __restrict__ o2g,
                       float* __restrict__ kp){
  int b = blockIdx.x, t = threadIdx.x;
  __shared__ float os[32];
  if (t < 32) os[t] = o2g[b*32 + t];
  __syncthreads();
  float acc = 0.f;
  #pragma unroll
  for (int i = 0; i < 32; i++) acc += os[i] * Wk[(size_t)(b*32 + i)*256 + t];
  kp[b*256 + t] = acc;
}

// finalize: nrm = ||o2||; kattn = (sum kp)/nrm; kb = (o2·bk)/nrm    1 x 256
__global__ void k_fin(const float* __restrict__ o2g, const float* __restrict__ kp,
                      const float* __restrict__ bk, float* __restrict__ kattn,
                      float* __restrict__ kbout){
  int t = threadIdx.x, lane = t & 63, wave = t >> 6;
  __shared__ float red[4], red2[4];
  float o2v = o2g[t];
  float sq = o2v*o2v;
  #pragma unroll
  for (int m = 1; m < 64; m <<= 1) sq += __shfl_xor(sq, m);
  if (lane == 0) red[wave] = sq;
  float cb = o2v * bk[t];
  #pragma unroll
  for (int m = 1; m < 64; m <<= 1) cb += __shfl_xor(cb, m);
  if (lane == 0) red2[wave] = cb;
  __syncthreads();
  float nrm = fmaxf(sqrtf(red[0]+red[1]+red[2]+red[3]), 1e-12f);
  float s = 0.f;
  #pragma unroll
  for (int b = 0; b < 8; b++) s += kp[b*256 + t];
  kattn[t] = s / nrm;
  if (t == 0) kbout[0] = (red2[0]+red2[1]+red2[2]+red2[3]) / nrm;
}

// ---------------- scores + online softmax stats ----------------
template<int BF>
__launch_bounds__(256)
__global__ void k_scores(const void* __restrict__ embsrc, const float* __restrict__ rk_g,
                         const int* __restrict__ mask, const float* __restrict__ kattn,
                         const float* __restrict__ kbp, float* __restrict__ scores,
                         float* __restrict__ p3stat){
  int tid = threadIdx.x, lane = tid & 63, wave = tid >> 6;
  int hl = lane & 31, h2 = lane >> 5;
  __shared__ float ka[256];
  ka[tid] = kattn[tid];
  __syncthreads();
  float kb = kbp[0];
  float kv[8];
  #pragma unroll
  for (int j = 0; j < 8; j++) kv[j] = ka[hl*8 + j];
  int gw = blockIdx.x*4 + wave;
  float m = -3.0e38f, z = 0.f;
  for (int p = gw; p < NN/2; p += 2048){
    int n = 2*p + h2;
    float d;
    if (BF){
      size_t addr = (size_t)(n >> 6)*32768 + (size_t)(hl >> 2)*4096
                  + (size_t)(n & 63)*64 + (size_t)(hl & 3)*16;
      uint4 g = *(const uint4*)((const unsigned char*)embsrc + addr);
      d  = bf2f((unsigned short)(g.x&0xffff))*kv[0] + bf2f((unsigned short)(g.x>>16))*kv[1];
      d += bf2f((unsigned short)(g.y&0xffff))*kv[2] + bf2f((unsigned short)(g.y>>16))*kv[3];
      d += bf2f((unsigned short)(g.z&0xffff))*kv[4] + bf2f((unsigned short)(g.z>>16))*kv[5];
      d += bf2f((unsigned short)(g.w&0xffff))*kv[6] + bf2f((unsigned short)(g.w>>16))*kv[7];
    } else {
      const float* ep = (const float*)embsrc + (size_t)n*256 + hl*8;
      float4 a = *(const float4*)ep, b = *(const float4*)(ep + 4);
      d = a.x*kv[0]+a.y*kv[1]+a.z*kv[2]+a.w*kv[3]+b.x*kv[4]+b.y*kv[5]+b.z*kv[6]+b.w*kv[7];
    }
    #pragma unroll
    for (int s = 1; s < 32; s <<= 1) d += __shfl_xor(d, s);
    if (hl == 0){
      float sc = (mask[n] == 0) ? ((d + kb) / rk_g[n]) : NEGV;
      scores[n] = sc;
      float M = fmaxf(m, sc);
      z = z*expf(m - M) + expf(sc - M);
      m = M;
    }
  }
  float m2 = __shfl_xor(m, 32), z2 = __shfl_xor(z, 32);
  float M = fmaxf(m, m2); z = z*expf(m-M) + z2*expf(m2-M); m = M;
  __shared__ float rm[4], rz[4];
  if (lane == 0){ rm[wave] = m; rz[wave] = z; }
  __syncthreads();
  if (tid == 0){
    float Mx = rm[0], Z = rz[0];
    for (int w = 1; w < 4; w++){
      float M2 = fmaxf(Mx, rm[w]);
      Z = Z*expf(Mx - M2) + rz[w]*expf(rm[w] - M2);
      Mx = M2;
    }
    p3stat[blockIdx.x*2] = Mx; p3stat[blockIdx.x*2+1] = Z;
  }
}

__global__ void k_mz3(const float* __restrict__ p3stat, float* __restrict__ MZ3){
  int t = threadIdx.x;
  float m = p3stat[t*2], z = p3stat[t*2+1];
  {
    float m2 = p3stat[(t+256)*2], z2 = p3stat[(t+256)*2+1];
    float M = fmaxf(m, m2); z = z*expf(m-M) + z2*expf(m2-M); m = M;
  }
  #pragma unroll
  for (int mm = 1; mm < 64; mm <<= 1){
    float ms = __shfl_xor(m, mm), zs = __shfl_xor(z, mm);
    float Mx = fmaxf(m, ms); z = z*expf(m-Mx) + zs*expf(ms-Mx); m = Mx;
  }
  __shared__ float rm[4], rz[4];
  if ((t&63)==0){ rm[t>>6]=m; rz[t>>6]=z; }
  __syncthreads();
  if (t==0){
    float M=rm[0], Z=rz[0];
    for (int w=1; w<4; w++){ float Mx=fmaxf(M,rm[w]); Z=Z*expf(M-Mx)+rz[w]*expf(rm[w]-Mx); M=Mx; }
    MZ3[0]=M; MZ3[1]=Z;
  }
}

__global__ void k_probs(const float* __restrict__ scores, const float* __restrict__ MZ3,
                        float* __restrict__ out){
  float M = MZ3[0], iZ = 1.0f / MZ3[1];
  for (int n = blockIdx.x*256 + threadIdx.x; n < NN; n += 512*256)
    out[n] = expf(scores[n] - M) * iZ;
}

// ---------------- launcher ----------------
extern "C" void kernel_launch(void* const* d_in, const int* in_sizes, int n_in,
                              void* d_out, int out_size, void* d_ws, size_t ws_size,
                              hipStream_t stream){
  (void)in_sizes; (void)n_in; (void)out_size;
  const float* ctx = (const float*)d_in[0];
  const float* emb = (const float*)d_in[1];
  const int*   mask= (const int*)d_in[2];
  const float* Wc  = (const float*)d_in[3];
  const float* bc  = (const float*)d_in[4];
  const float* Wk  = (const float*)d_in[5];
  const float* bk  = (const float*)d_in[6];
  const float* Wv  = (const float*)d_in[7];
  const float* bv  = (const float*)d_in[8];
  const float* ipw = (const float*)d_in[9];
  const float* ipb = (const float*)d_in[10];
  const float* opw = (const float*)d_in[11];
  const float* opb = (const float*)d_in[12];
  const float* Wo  = (const float*)d_in[13];
  const float* bo  = (const float*)d_in[14];
  float* out = (float*)d_out;
  char* ws = (char*)d_ws;

  float* rk     = (float*)(ws + OFF_RK);
  float* rv     = (float*)(ws + OFF_RV);
  float* logits = (float*)(ws + OFF_LOGITS);
  float* scores = (float*)(ws + OFF_SCORES);
  float* query  = (float*)(ws + OFF_QUERY);
  float* q2     = (float*)(ws + OFF_Q2);
  float* A2     = (float*)(ws + OFF_A2);
  float* consts = (float*)(ws + OFF_CONSTS);
  unsigned char* bimg = (unsigned char*)(ws + OFF_BIMG);
  float* lstat  = (float*)(ws + OFF_LSTAT);
  float* MZ     = (float*)(ws + OFF_MZ);
  float* kattn  = (float*)(ws + OFF_KATTN);
  float* kb     = (float*)(ws + OFF_KB);
  float* upart  = (float*)(ws + OFF_UPART);
  float* tpart  = (float*)(ws + OFF_TPART);
  float* U      = (float*)(ws + OFF_U);
  float* T      = (float*)(ws + OFF_T);
  float* p3stat = (float*)(ws + OFF_P3STAT);
  float* MZ3    = (float*)(ws + OFF_MZ3);
  // time-shared scratch inside UPART region
  float* AH   = (float*)(ws + OFF_UPART + 32768);
  float* A2p  = (float*)(ws + OFF_UPART + 65536);
  float* sh2g = (float*)(ws + OFF_UPART + 0);
  float* a1g  = (float*)(ws + OFF_UPART + 8192);
  float* o1g  = (float*)(ws + OFF_UPART + 9216);
  float* o2g  = (float*)(ws + OFF_UPART + 10240);
  float* kp   = (float*)(ws + OFF_UPART + 11264);

  const bool bf = ws_size >= WS_NEED_BF;
  unsigned char* ebf = bf ? (unsigned char*)(ws + OFF_EMBBF) : nullptr;

  k_prep1 <<<32,  256, 0, stream>>>(ctx, Wc, bc, query);
  k_prep2 <<<32,  256, 0, stream>>>(ipw, ipb, query, q2);
  k_prep3 <<<8,   256, 0, stream>>>(ipw, ipb, q2, AH, consts);
  k_prep4 <<<64,  256, 0, stream>>>(Wk, AH, A2p);
  k_prep5 <<<8,   256, 0, stream>>>(A2p, AH, bk, A2, consts);
  k_bimg  <<<66,  256, 0, stream>>>(Wk, Wv, A2, bimg);
  k_main  <<<3125,512, 0, stream>>>(emb, bimg, mask, consts, rk, rv, logits, ebf);
  k_lstats<<<128, 256, 0, stream>>>(logits, lstat);
  k_mz    <<<1,   64,  0, stream>>>(lstat, MZ);
  if (bf) k_wsum<1><<<512, 256, 0, stream>>>(ebf, logits, rv, MZ, upart, tpart);
  else    k_wsum<0><<<512, 256, 0, stream>>>(emb, logits, rv, MZ, upart, tpart);
  k_ured  <<<64,  256, 0, stream>>>(upart, tpart, U, T);
  k_att1  <<<32,  256, 0, stream>>>(U, T, MZ, Wv, bv, sh2g);
  k_att2  <<<32,  256, 0, stream>>>(ipw, ipb, sh2g, a1g);
  k_matvec<<<32,  256, 0, stream>>>(opw, opb, a1g, o1g);
  k_matvec<<<32,  256, 0, stream>>>(Wo, bo, o1g, o2g);
  k_att5  <<<8,   256, 0, stream>>>(Wk, o2g, kp);
  k_fin   <<<1,   256, 0, stream>>>(o2g, kp, bk, kattn, kb);
  if (bf) k_scores<1><<<512, 256, 0, stream>>>(ebf, rk, mask, kattn, kb, scores, p3stat);
  else    k_scores<0><<<512, 256, 0, stream>>>(emb, rk, mask, kattn, kb, scores, p3stat);
  k_mz3   <<<1,   256, 0, stream>>>(p3stat, MZ3);
  k_probs <<<512, 256, 0, stream>>>(scores, MZ3, out);
}